// Round 3
// baseline (643.556 us; speedup 1.0000x reference)
//
#include <hip/hip_runtime.h>

#define NROWS 65536
#define KC    1024
#define DIM   128
#define W_DIST 5e-5f

typedef short  bf16x8 __attribute__((ext_vector_type(8)));
typedef float  f32x4  __attribute__((ext_vector_type(4)));

__device__ __forceinline__ unsigned short f2bf_rne(float f) {
    unsigned int u = __float_as_uint(f);
    u += 0x7FFFu + ((u >> 16) & 1u);
    return (unsigned short)(u >> 16);
}
__device__ __forceinline__ float bf2f(unsigned short h) {
    return __uint_as_float(((unsigned int)h) << 16);
}

// numpy pairwise sum-of-squares for n=128 (8 stride-8 accumulators, tree combine)
__device__ __forceinline__ float np_sumsq_128(const float* v) {
    float r[8];
    #pragma unroll
    for (int j = 0; j < 8; ++j) r[j] = __fmul_rn(v[j], v[j]);
    #pragma unroll
    for (int i = 1; i < 16; ++i)
        #pragma unroll
        for (int j = 0; j < 8; ++j)
            r[j] = __fadd_rn(r[j], __fmul_rn(v[i * 8 + j], v[i * 8 + j]));
    return __fadd_rn(__fadd_rn(__fadd_rn(r[0], r[1]), __fadd_rn(r[2], r[3])),
                     __fadd_rn(__fadd_rn(r[4], r[5]), __fadd_rn(r[6], r[7])));
}

// ---- split x into bf16 hi/mid: 8 elems per thread --------------------------
__global__ __launch_bounds__(256) void split_x(const float* __restrict__ x,
        unsigned short* __restrict__ xh, unsigned short* __restrict__ xm) {
    const int t = blockIdx.x * 256 + threadIdx.x;   // 1048576 threads
    const float4* p = reinterpret_cast<const float4*>(x) + (size_t)t * 2;
    float4 a = p[0], b = p[1];
    float f[8] = {a.x, a.y, a.z, a.w, b.x, b.y, b.z, b.w};
    unsigned int h[8], m[8];
    #pragma unroll
    for (int i = 0; i < 8; ++i) {
        unsigned short hh = f2bf_rne(f[i]);
        h[i] = hh;
        m[i] = f2bf_rne(f[i] - bf2f(hh));
    }
    uint4 vh = {h[0] | (h[1] << 16), h[2] | (h[3] << 16),
                h[4] | (h[5] << 16), h[6] | (h[7] << 16)};
    uint4 vm = {m[0] | (m[1] << 16), m[2] | (m[3] << 16),
                m[4] | (m[5] << 16), m[6] | (m[7] << 16)};
    *reinterpret_cast<uint4*>(xh + (size_t)t * 8) = vh;
    *reinterpret_cast<uint4*>(xm + (size_t)t * 8) = vm;
}

// ---- split codebook into bf16 hi/mid -------------------------------------
__global__ __launch_bounds__(256) void split_e(const float* __restrict__ emb,
        unsigned short* __restrict__ eh, unsigned short* __restrict__ em) {
    const int t = blockIdx.x * 256 + threadIdx.x;   // 16384 threads
    const float4* p = reinterpret_cast<const float4*>(emb) + (size_t)t * 2;
    float4 a = p[0], b = p[1];
    float f[8] = {a.x, a.y, a.z, a.w, b.x, b.y, b.z, b.w};
    unsigned int h[8], m[8];
    #pragma unroll
    for (int i = 0; i < 8; ++i) {
        unsigned short hh = f2bf_rne(f[i]);
        h[i] = hh;
        m[i] = f2bf_rne(f[i] - bf2f(hh));
    }
    uint4 vh = {h[0] | (h[1] << 16), h[2] | (h[3] << 16),
                h[4] | (h[5] << 16), h[6] | (h[7] << 16)};
    uint4 vm = {m[0] | (m[1] << 16), m[2] | (m[3] << 16),
                m[4] | (m[5] << 16), m[6] | (m[7] << 16)};
    *reinterpret_cast<uint4*>(eh + (size_t)t * 8) = vh;
    *reinterpret_cast<uint4*>(em + (size_t)t * 8) = vm;
}

// ---- codebook norms: numpy-pairwise exact + -0.5x for MFMA init -----------
__global__ __launch_bounds__(256) void vq_norms(const float* __restrict__ emb,
        float* __restrict__ enorm, float* __restrict__ neg_half) {
    const int k = blockIdx.x * 256 + threadIdx.x;
    if (k >= KC) return;
    float v[DIM];
    const float4* e = reinterpret_cast<const float4*>(emb + (size_t)k * DIM);
    #pragma unroll
    for (int i = 0; i < 32; ++i) {
        float4 t = e[i];
        v[i * 4 + 0] = t.x; v[i * 4 + 1] = t.y;
        v[i * 4 + 2] = t.z; v[i * 4 + 3] = t.w;
    }
    float n = np_sumsq_128(v);
    enorm[k] = n;
    neg_half[k] = -0.5f * n;
}

// ---- main MFMA distance + top-2 kernel ------------------------------------
// C = E . X^T  via mfma_f32_16x16x32_bf16, split products Eh*Xh+Eh*Xm+Em*Xh.
// A-frag: lane holds A[L&15][(L>>4)*8 + j]; B-frag: B[(L>>4)*8+j][L&15];
// C: C[(L>>4)*4 + r][L&15]  (m89-verified layout).
__global__ __launch_bounds__(256, 3) void vq_mfma(
        const unsigned short* __restrict__ xh, const unsigned short* __restrict__ xm,
        const unsigned short* __restrict__ eh, const unsigned short* __restrict__ em,
        const float* __restrict__ neg_half,
        int* __restrict__ bestk, float* __restrict__ idx_out,
        int* __restrict__ fb_cnt, int* __restrict__ fb_rows) {
    const int lane = threadIdx.x & 63;
    const int wid  = threadIdx.x >> 6;
    const int rtile = blockIdx.x * 128 + wid * 32;   // 32 rows per wave
    const int lr = lane & 15;
    const int lg = lane >> 4;

    // X fragments resident for whole kernel: [nt][kc]
    bf16x8 fxh[2][4], fxm[2][4];
    #pragma unroll
    for (int nt = 0; nt < 2; ++nt) {
        const size_t row = rtile + nt * 16 + lr;
        const unsigned short* ph = xh + row * DIM + lg * 8;
        const unsigned short* pm = xm + row * DIM + lg * 8;
        #pragma unroll
        for (int kc = 0; kc < 4; ++kc) {
            fxh[nt][kc] = *reinterpret_cast<const bf16x8*>(ph + kc * 32);
            fxm[nt][kc] = *reinterpret_cast<const bf16x8*>(pm + kc * 32);
        }
    }

    float m1_0 = 1e30f, m2_0 = 1e30f; int k1_0 = 0;
    float m1_1 = 1e30f, m2_1 = 1e30f; int k1_1 = 0;

    for (int m = 0; m < 64; ++m) {
        const int m0 = m * 16;
        const f32x4 einit = *reinterpret_cast<const f32x4*>(neg_half + m0 + lg * 4);
        f32x4 acc0 = einit, acc1 = einit;
        const unsigned short* peh = eh + (size_t)(m0 + lr) * DIM + lg * 8;
        const unsigned short* pem = em + (size_t)(m0 + lr) * DIM + lg * 8;
        #pragma unroll
        for (int kc = 0; kc < 4; ++kc) {
            bf16x8 feh = *reinterpret_cast<const bf16x8*>(peh + kc * 32);
            bf16x8 fem = *reinterpret_cast<const bf16x8*>(pem + kc * 32);
            acc0 = __builtin_amdgcn_mfma_f32_16x16x32_bf16(feh, fxh[0][kc], acc0, 0, 0, 0);
            acc1 = __builtin_amdgcn_mfma_f32_16x16x32_bf16(feh, fxh[1][kc], acc1, 0, 0, 0);
            acc0 = __builtin_amdgcn_mfma_f32_16x16x32_bf16(feh, fxm[0][kc], acc0, 0, 0, 0);
            acc1 = __builtin_amdgcn_mfma_f32_16x16x32_bf16(feh, fxm[1][kc], acc1, 0, 0, 0);
            acc0 = __builtin_amdgcn_mfma_f32_16x16x32_bf16(fem, fxh[0][kc], acc0, 0, 0, 0);
            acc1 = __builtin_amdgcn_mfma_f32_16x16x32_bf16(fem, fxh[1][kc], acc1, 0, 0, 0);
        }
        const int kbase = m0 + lg * 4;
        #pragma unroll
        for (int r = 0; r < 4; ++r) {
            {   float v = -2.0f * acc0[r]; int kk = kbase + r;
                bool lt = v < m1_0;
                float t = fminf(m2_0, v);
                m2_0 = lt ? m1_0 : t;
                k1_0 = lt ? kk : k1_0;
                m1_0 = lt ? v : m1_0; }
            {   float v = -2.0f * acc1[r]; int kk = kbase + r;
                bool lt = v < m1_1;
                float t = fminf(m2_1, v);
                m2_1 = lt ? m1_1 : t;
                k1_1 = lt ? kk : k1_1;
                m1_1 = lt ? v : m1_1; }
        }
    }

    // merge the 4 lane-groups (each saw a disjoint k-subset) per row
    #pragma unroll
    for (int off = 16; off <= 32; off <<= 1) {
        {   float om1 = __shfl_xor(m1_0, off, 64);
            float om2 = __shfl_xor(m2_0, off, 64);
            int   ok1 = __shfl_xor(k1_0, off, 64);
            float hi = fmaxf(m1_0, om1);
            m2_0 = fminf(fminf(m2_0, om2), hi);
            bool take = om1 < m1_0;
            k1_0 = take ? ok1 : k1_0;
            m1_0 = fminf(m1_0, om1); }
        {   float om1 = __shfl_xor(m1_1, off, 64);
            float om2 = __shfl_xor(m2_1, off, 64);
            int   ok1 = __shfl_xor(k1_1, off, 64);
            float hi = fmaxf(m1_1, om1);
            m2_1 = fminf(fminf(m2_1, om2), hi);
            bool take = om1 < m1_1;
            k1_1 = take ? ok1 : k1_1;
            m1_1 = fminf(m1_1, om1); }
    }

    if (lane < 16) {
        #pragma unroll
        for (int nt = 0; nt < 2; ++nt) {
            const int row = rtile + nt * 16 + lane;
            float m1 = nt ? m1_1 : m1_0;
            float m2 = nt ? m2_1 : m2_0;
            int   k1 = nt ? k1_1 : k1_0;
            if (m2 - m1 < W_DIST) {          // ambiguous under rounding: refine
                int slot = atomicAdd(fb_cnt, 1);
                fb_rows[slot] = row;
            } else {
                bestk[row] = k1;
                idx_out[row] = (float)k1;
            }
        }
    }
}

// ---- exact fallback: one wave per ambiguous row, bit-replicated formula ----
__global__ __launch_bounds__(256, 2) void vq_fallback(
        const float* __restrict__ x, const float* __restrict__ emb,
        const float* __restrict__ enorm,
        const int* __restrict__ fb_cnt, const int* __restrict__ fb_rows,
        int* __restrict__ bestk, float* __restrict__ idx_out) {
    const int lane = threadIdx.x & 63;
    const int wgid = blockIdx.x * 4 + (threadIdx.x >> 6);
    const int nw = gridDim.x * 4;
    const int n = *fb_cnt;
    for (int i = wgid; i < n; i += nw) {
        const int row = fb_rows[i];
        const float4* xr = reinterpret_cast<const float4*>(x + (size_t)row * DIM);
        // numpy-pairwise ||x||^2 (identical rounding to reference)
        float r8[8];
        {
            float4 a = xr[0], b = xr[1];
            r8[0] = __fmul_rn(a.x, a.x); r8[1] = __fmul_rn(a.y, a.y);
            r8[2] = __fmul_rn(a.z, a.z); r8[3] = __fmul_rn(a.w, a.w);
            r8[4] = __fmul_rn(b.x, b.x); r8[5] = __fmul_rn(b.y, b.y);
            r8[6] = __fmul_rn(b.z, b.z); r8[7] = __fmul_rn(b.w, b.w);
            for (int q = 1; q < 16; ++q) {
                float4 c = xr[2 * q], d = xr[2 * q + 1];
                r8[0] = __fadd_rn(r8[0], __fmul_rn(c.x, c.x));
                r8[1] = __fadd_rn(r8[1], __fmul_rn(c.y, c.y));
                r8[2] = __fadd_rn(r8[2], __fmul_rn(c.z, c.z));
                r8[3] = __fadd_rn(r8[3], __fmul_rn(c.w, c.w));
                r8[4] = __fadd_rn(r8[4], __fmul_rn(d.x, d.x));
                r8[5] = __fadd_rn(r8[5], __fmul_rn(d.y, d.y));
                r8[6] = __fadd_rn(r8[6], __fmul_rn(d.z, d.z));
                r8[7] = __fadd_rn(r8[7], __fmul_rn(d.w, d.w));
            }
        }
        float xnorm = __fadd_rn(
            __fadd_rn(__fadd_rn(r8[0], r8[1]), __fadd_rn(r8[2], r8[3])),
            __fadd_rn(__fadd_rn(r8[4], r8[5]), __fadd_rn(r8[6], r8[7])));

        float bv = 3.402823466e38f; int bk = 0;
        for (int j = 0; j < 16; ++j) {
            const int k = lane + j * 64;     // ascending k per lane
            const float4* er = reinterpret_cast<const float4*>(emb + (size_t)k * DIM);
            float d0 = 0.f, d1 = 0.f, d2 = 0.f, d3 = 0.f;
            #pragma unroll
            for (int q = 0; q < 32; ++q) {
                float4 ev = er[q]; float4 xv = xr[q];
                d0 = fmaf(xv.x, ev.x, d0);
                d1 = fmaf(xv.y, ev.y, d1);
                d2 = fmaf(xv.z, ev.z, d2);
                d3 = fmaf(xv.w, ev.w, d3);
            }
            float dot = __fadd_rn(__fadd_rn(d0, d1), __fadd_rn(d2, d3));
            float s = __fsub_rn(__fadd_rn(xnorm, enorm[k]), __fmul_rn(2.0f, dot));
            if (s < bv) { bv = s; bk = k; }
        }
        // lexicographic (value, k) wave-min — first-occurrence semantics
        #pragma unroll
        for (int off = 1; off < 64; off <<= 1) {
            float ov = __shfl_xor(bv, off, 64);
            int   ok = __shfl_xor(bk, off, 64);
            bool take = (ov < bv) || (ov == bv && ok < bk);
            bv = take ? ov : bv;
            bk = take ? ok : bk;
        }
        if (lane == 0) { bestk[row] = bk; idx_out[row] = (float)bk; }
    }
}

// ---- gather quantized rows + loss -----------------------------------------
__global__ __launch_bounds__(256) void vq_gather(
        const float* __restrict__ x, const float* __restrict__ emb,
        const int* __restrict__ bestk, float* __restrict__ quant,
        double* __restrict__ loss_sum) {
    const int t = blockIdx.x * 256 + threadIdx.x;   // 2097152 threads, 4 elems
    const int r = t >> 5;
    const int c = (t & 31) * 4;
    const int bk = bestk[r];
    float4 e4 = *reinterpret_cast<const float4*>(emb + (size_t)bk * DIM + c);
    float4 x4 = *reinterpret_cast<const float4*>(x + (size_t)r * DIM + c);
    float* q = quant + (size_t)r * DIM + c;   // base misaligned by 1 float
    q[0] = e4.x; q[1] = e4.y; q[2] = e4.z; q[3] = e4.w;
    float dx = e4.x - x4.x, dy = e4.y - x4.y;
    float dz = e4.z - x4.z, dw = e4.w - x4.w;
    float acc = fmaf(dx, dx, fmaf(dy, dy, fmaf(dz, dz, dw * dw)));
    #pragma unroll
    for (int off = 32; off > 0; off >>= 1) acc += __shfl_down(acc, off, 64);
    if ((threadIdx.x & 63) == 0) atomicAdd(loss_sum, (double)acc);
}

__global__ void vq_loss(const double* __restrict__ loss_sum, float* __restrict__ out) {
    out[0] = (float)(*loss_sum * (1.25 / 8388608.0));
}

extern "C" void kernel_launch(void* const* d_in, const int* in_sizes, int n_in,
                              void* d_out, int out_size, void* d_ws, size_t ws_size,
                              hipStream_t stream) {
    const float* x   = (const float*)d_in[0];   // [32,2048,128] f32
    const float* emb = (const float*)d_in[1];   // [1024,128] f32

    float* out      = (float*)d_out;
    float* loss_out = out;
    float* quant    = out + 1;                        // [8388608]
    float* idx_out  = out + 1 + (size_t)NROWS * DIM;  // [65536] as float

    // bf16 X splits staged inside the (later overwritten) quant region,
    // at a 16-B-aligned offset.
    unsigned short* xh = (unsigned short*)((char*)d_out + 16);
    unsigned short* xm = xh + (size_t)NROWS * DIM;    // 16 MB each

    char* ws = (char*)d_ws;
    double* loss_sum = (double*)ws;                     // [0,8)
    int*    fb_cnt   = (int*)(ws + 8);                  // [8,12)
    float*  enorm    = (float*)(ws + 1024);             // 4 KB
    float*  neg_half = (float*)(ws + 5120);             // 4 KB
    int*    fb_rows  = (int*)(ws + 16384);              // 256 KB
    int*    bestk    = (int*)(ws + 278528);             // 256 KB
    unsigned short* eh = (unsigned short*)(ws + 557056); // 256 KB
    unsigned short* em = (unsigned short*)(ws + 819200); // 256 KB

    hipMemsetAsync(ws, 0, 16, stream);
    split_x<<<4096, 256, 0, stream>>>(x, xh, xm);
    split_e<<<64, 256, 0, stream>>>(emb, eh, em);
    vq_norms<<<4, 256, 0, stream>>>(emb, enorm, neg_half);
    vq_mfma<<<512, 256, 0, stream>>>(xh, xm, eh, em, neg_half,
                                     bestk, idx_out, fb_cnt, fb_rows);
    vq_fallback<<<256, 256, 0, stream>>>(x, emb, enorm, fb_cnt, fb_rows,
                                         bestk, idx_out);
    vq_gather<<<8192, 256, 0, stream>>>(x, emb, bestk, quant, loss_sum);
    vq_loss<<<1, 1, 0, stream>>>(loss_sum, loss_out);
}

// Round 4
// 255.990 us; speedup vs baseline: 2.5140x; 2.5140x over previous
//
#include <hip/hip_runtime.h>

#define NROWS 65536
#define KC    1024
#define DIM   128
#define W_DIST 5e-5f

typedef short  bf16x8 __attribute__((ext_vector_type(8)));
typedef float  f32x4  __attribute__((ext_vector_type(4)));

__device__ __forceinline__ unsigned short f2bf_rne(float f) {
    unsigned int u = __float_as_uint(f);
    u += 0x7FFFu + ((u >> 16) & 1u);
    return (unsigned short)(u >> 16);
}
__device__ __forceinline__ float bf2f(unsigned short h) {
    return __uint_as_float(((unsigned int)h) << 16);
}

// numpy pairwise sum-of-squares for n=128 (8 stride-8 accumulators, tree combine)
__device__ __forceinline__ float np_sumsq_128(const float* v) {
    float r[8];
    #pragma unroll
    for (int j = 0; j < 8; ++j) r[j] = __fmul_rn(v[j], v[j]);
    #pragma unroll
    for (int i = 1; i < 16; ++i)
        #pragma unroll
        for (int j = 0; j < 8; ++j)
            r[j] = __fadd_rn(r[j], __fmul_rn(v[i * 8 + j], v[i * 8 + j]));
    return __fadd_rn(__fadd_rn(__fadd_rn(r[0], r[1]), __fadd_rn(r[2], r[3])),
                     __fadd_rn(__fadd_rn(r[4], r[5]), __fadd_rn(r[6], r[7])));
}

// ---- split x into bf16 hi/mid: 8 elems per thread --------------------------
__global__ __launch_bounds__(256) void split_x(const float* __restrict__ x,
        unsigned short* __restrict__ xh, unsigned short* __restrict__ xm) {
    const int t = blockIdx.x * 256 + threadIdx.x;   // 1048576 threads
    const float4* p = reinterpret_cast<const float4*>(x) + (size_t)t * 2;
    float4 a = p[0], b = p[1];
    float f[8] = {a.x, a.y, a.z, a.w, b.x, b.y, b.z, b.w};
    unsigned int h[8], m[8];
    #pragma unroll
    for (int i = 0; i < 8; ++i) {
        unsigned short hh = f2bf_rne(f[i]);
        h[i] = hh;
        m[i] = f2bf_rne(f[i] - bf2f(hh));
    }
    uint4 vh = {h[0] | (h[1] << 16), h[2] | (h[3] << 16),
                h[4] | (h[5] << 16), h[6] | (h[7] << 16)};
    uint4 vm = {m[0] | (m[1] << 16), m[2] | (m[3] << 16),
                m[4] | (m[5] << 16), m[6] | (m[7] << 16)};
    *reinterpret_cast<uint4*>(xh + (size_t)t * 8) = vh;
    *reinterpret_cast<uint4*>(xm + (size_t)t * 8) = vm;
}

// ---- split codebook into bf16 hi/mid -------------------------------------
__global__ __launch_bounds__(256) void split_e(const float* __restrict__ emb,
        unsigned short* __restrict__ eh, unsigned short* __restrict__ em) {
    const int t = blockIdx.x * 256 + threadIdx.x;   // 16384 threads
    const float4* p = reinterpret_cast<const float4*>(emb) + (size_t)t * 2;
    float4 a = p[0], b = p[1];
    float f[8] = {a.x, a.y, a.z, a.w, b.x, b.y, b.z, b.w};
    unsigned int h[8], m[8];
    #pragma unroll
    for (int i = 0; i < 8; ++i) {
        unsigned short hh = f2bf_rne(f[i]);
        h[i] = hh;
        m[i] = f2bf_rne(f[i] - bf2f(hh));
    }
    uint4 vh = {h[0] | (h[1] << 16), h[2] | (h[3] << 16),
                h[4] | (h[5] << 16), h[6] | (h[7] << 16)};
    uint4 vm = {m[0] | (m[1] << 16), m[2] | (m[3] << 16),
                m[4] | (m[5] << 16), m[6] | (m[7] << 16)};
    *reinterpret_cast<uint4*>(eh + (size_t)t * 8) = vh;
    *reinterpret_cast<uint4*>(em + (size_t)t * 8) = vm;
}

// ---- codebook norms: numpy-pairwise exact + -0.5x for MFMA init -----------
__global__ __launch_bounds__(256) void vq_norms(const float* __restrict__ emb,
        float* __restrict__ enorm, float* __restrict__ neg_half) {
    const int k = blockIdx.x * 256 + threadIdx.x;
    if (k >= KC) return;
    float v[DIM];
    const float4* e = reinterpret_cast<const float4*>(emb + (size_t)k * DIM);
    #pragma unroll
    for (int i = 0; i < 32; ++i) {
        float4 t = e[i];
        v[i * 4 + 0] = t.x; v[i * 4 + 1] = t.y;
        v[i * 4 + 2] = t.z; v[i * 4 + 3] = t.w;
    }
    float n = np_sumsq_128(v);
    enorm[k] = n;
    neg_half[k] = -0.5f * n;
}

// ---- main MFMA distance + top-2 kernel ------------------------------------
// C = E . X^T  via mfma_f32_16x16x32_bf16, split products Eh*Xh+Eh*Xm+Em*Xh.
__global__ __launch_bounds__(256, 3) void vq_mfma(
        const unsigned short* __restrict__ xh, const unsigned short* __restrict__ xm,
        const unsigned short* __restrict__ eh, const unsigned short* __restrict__ em,
        const float* __restrict__ neg_half,
        int* __restrict__ bestk, float* __restrict__ idx_out,
        int* __restrict__ fb_cnt, int* __restrict__ fb_rows) {
    const int lane = threadIdx.x & 63;
    const int wid  = threadIdx.x >> 6;
    const int rtile = blockIdx.x * 128 + wid * 32;   // 32 rows per wave
    const int lr = lane & 15;
    const int lg = lane >> 4;

    // X fragments resident for whole kernel: [nt][kc]
    bf16x8 fxh[2][4], fxm[2][4];
    #pragma unroll
    for (int nt = 0; nt < 2; ++nt) {
        const size_t row = rtile + nt * 16 + lr;
        const unsigned short* ph = xh + row * DIM + lg * 8;
        const unsigned short* pm = xm + row * DIM + lg * 8;
        #pragma unroll
        for (int kc = 0; kc < 4; ++kc) {
            fxh[nt][kc] = *reinterpret_cast<const bf16x8*>(ph + kc * 32);
            fxm[nt][kc] = *reinterpret_cast<const bf16x8*>(pm + kc * 32);
        }
    }

    float m1_0 = 1e30f, m2_0 = 1e30f; int k1_0 = 0;
    float m1_1 = 1e30f, m2_1 = 1e30f; int k1_1 = 0;

    for (int m = 0; m < 64; ++m) {
        const int m0 = m * 16;
        const f32x4 einit = *reinterpret_cast<const f32x4*>(neg_half + m0 + lg * 4);
        f32x4 acc0 = einit, acc1 = einit;
        const unsigned short* peh = eh + (size_t)(m0 + lr) * DIM + lg * 8;
        const unsigned short* pem = em + (size_t)(m0 + lr) * DIM + lg * 8;
        #pragma unroll
        for (int kc = 0; kc < 4; ++kc) {
            bf16x8 feh = *reinterpret_cast<const bf16x8*>(peh + kc * 32);
            bf16x8 fem = *reinterpret_cast<const bf16x8*>(pem + kc * 32);
            acc0 = __builtin_amdgcn_mfma_f32_16x16x32_bf16(feh, fxh[0][kc], acc0, 0, 0, 0);
            acc1 = __builtin_amdgcn_mfma_f32_16x16x32_bf16(feh, fxh[1][kc], acc1, 0, 0, 0);
            acc0 = __builtin_amdgcn_mfma_f32_16x16x32_bf16(feh, fxm[0][kc], acc0, 0, 0, 0);
            acc1 = __builtin_amdgcn_mfma_f32_16x16x32_bf16(feh, fxm[1][kc], acc1, 0, 0, 0);
            acc0 = __builtin_amdgcn_mfma_f32_16x16x32_bf16(fem, fxh[0][kc], acc0, 0, 0, 0);
            acc1 = __builtin_amdgcn_mfma_f32_16x16x32_bf16(fem, fxh[1][kc], acc1, 0, 0, 0);
        }
        const int kbase = m0 + lg * 4;
        #pragma unroll
        for (int r = 0; r < 4; ++r) {
            {   float v = -2.0f * acc0[r]; int kk = kbase + r;
                bool lt = v < m1_0;
                float t = fminf(m2_0, v);
                m2_0 = lt ? m1_0 : t;
                k1_0 = lt ? kk : k1_0;
                m1_0 = lt ? v : m1_0; }
            {   float v = -2.0f * acc1[r]; int kk = kbase + r;
                bool lt = v < m1_1;
                float t = fminf(m2_1, v);
                m2_1 = lt ? m1_1 : t;
                k1_1 = lt ? kk : k1_1;
                m1_1 = lt ? v : m1_1; }
        }
    }

    // merge the 4 lane-groups (each saw a disjoint k-subset) per row
    #pragma unroll
    for (int off = 16; off <= 32; off <<= 1) {
        {   float om1 = __shfl_xor(m1_0, off, 64);
            float om2 = __shfl_xor(m2_0, off, 64);
            int   ok1 = __shfl_xor(k1_0, off, 64);
            float hi = fmaxf(m1_0, om1);
            m2_0 = fminf(fminf(m2_0, om2), hi);
            bool take = om1 < m1_0;
            k1_0 = take ? ok1 : k1_0;
            m1_0 = fminf(m1_0, om1); }
        {   float om1 = __shfl_xor(m1_1, off, 64);
            float om2 = __shfl_xor(m2_1, off, 64);
            int   ok1 = __shfl_xor(k1_1, off, 64);
            float hi = fmaxf(m1_1, om1);
            m2_1 = fminf(fminf(m2_1, om2), hi);
            bool take = om1 < m1_1;
            k1_1 = take ? ok1 : k1_1;
            m1_1 = fminf(m1_1, om1); }
    }

    if (lane < 16) {
        #pragma unroll
        for (int nt = 0; nt < 2; ++nt) {
            const int row = rtile + nt * 16 + lane;
            float m1 = nt ? m1_1 : m1_0;
            float m2 = nt ? m2_1 : m2_0;
            int   k1 = nt ? k1_1 : k1_0;
            if (m2 - m1 < W_DIST) {          // ambiguous under rounding: refine
                int slot = atomicAdd(fb_cnt, 1);
                fb_rows[slot] = row;
            } else {
                bestk[row] = k1;
                idx_out[row] = (float)k1;
            }
        }
    }
}

// ---- exact fallback: one wave per ambiguous row, bit-replicated formula ----
__global__ __launch_bounds__(256, 2) void vq_fallback(
        const float* __restrict__ x, const float* __restrict__ emb,
        const float* __restrict__ enorm,
        const int* __restrict__ fb_cnt, const int* __restrict__ fb_rows,
        int* __restrict__ bestk, float* __restrict__ idx_out) {
    const int lane = threadIdx.x & 63;
    const int wgid = blockIdx.x * 4 + (threadIdx.x >> 6);
    const int nw = gridDim.x * 4;
    const int n = *fb_cnt;
    for (int i = wgid; i < n; i += nw) {
        const int row = fb_rows[i];
        const float4* xr = reinterpret_cast<const float4*>(x + (size_t)row * DIM);
        float r8[8];
        {
            float4 a = xr[0], b = xr[1];
            r8[0] = __fmul_rn(a.x, a.x); r8[1] = __fmul_rn(a.y, a.y);
            r8[2] = __fmul_rn(a.z, a.z); r8[3] = __fmul_rn(a.w, a.w);
            r8[4] = __fmul_rn(b.x, b.x); r8[5] = __fmul_rn(b.y, b.y);
            r8[6] = __fmul_rn(b.z, b.z); r8[7] = __fmul_rn(b.w, b.w);
            for (int q = 1; q < 16; ++q) {
                float4 c = xr[2 * q], d = xr[2 * q + 1];
                r8[0] = __fadd_rn(r8[0], __fmul_rn(c.x, c.x));
                r8[1] = __fadd_rn(r8[1], __fmul_rn(c.y, c.y));
                r8[2] = __fadd_rn(r8[2], __fmul_rn(c.z, c.z));
                r8[3] = __fadd_rn(r8[3], __fmul_rn(c.w, c.w));
                r8[4] = __fadd_rn(r8[4], __fmul_rn(d.x, d.x));
                r8[5] = __fadd_rn(r8[5], __fmul_rn(d.y, d.y));
                r8[6] = __fadd_rn(r8[6], __fmul_rn(d.z, d.z));
                r8[7] = __fadd_rn(r8[7], __fmul_rn(d.w, d.w));
            }
        }
        float xnorm = __fadd_rn(
            __fadd_rn(__fadd_rn(r8[0], r8[1]), __fadd_rn(r8[2], r8[3])),
            __fadd_rn(__fadd_rn(r8[4], r8[5]), __fadd_rn(r8[6], r8[7])));

        float bv = 3.402823466e38f; int bk = 0;
        for (int j = 0; j < 16; ++j) {
            const int k = lane + j * 64;     // ascending k per lane
            const float4* er = reinterpret_cast<const float4*>(emb + (size_t)k * DIM);
            float d0 = 0.f, d1 = 0.f, d2 = 0.f, d3 = 0.f;
            #pragma unroll
            for (int q = 0; q < 32; ++q) {
                float4 ev = er[q]; float4 xv = xr[q];
                d0 = fmaf(xv.x, ev.x, d0);
                d1 = fmaf(xv.y, ev.y, d1);
                d2 = fmaf(xv.z, ev.z, d2);
                d3 = fmaf(xv.w, ev.w, d3);
            }
            float dot = __fadd_rn(__fadd_rn(d0, d1), __fadd_rn(d2, d3));
            float s = __fsub_rn(__fadd_rn(xnorm, enorm[k]), __fmul_rn(2.0f, dot));
            if (s < bv) { bv = s; bk = k; }
        }
        #pragma unroll
        for (int off = 1; off < 64; off <<= 1) {
            float ov = __shfl_xor(bv, off, 64);
            int   ok = __shfl_xor(bk, off, 64);
            bool take = (ov < bv) || (ov == bv && ok < bk);
            bv = take ? ov : bv;
            bk = take ? ok : bk;
        }
        if (lane == 0) { bestk[row] = bk; idx_out[row] = (float)bk; }
    }
}

// ---- gather quantized rows + per-block loss partials (no atomics) ---------
__global__ __launch_bounds__(256) void vq_gather(
        const float* __restrict__ x, const float* __restrict__ emb,
        const int* __restrict__ bestk, float* __restrict__ quant,
        double* __restrict__ partials) {
    const int t = blockIdx.x * 256 + threadIdx.x;   // 1048576 threads, 8 elems
    const int r = t >> 4;
    const int c = (t & 15) * 8;
    const int bk = bestk[r];
    const float4* ep = reinterpret_cast<const float4*>(emb + (size_t)bk * DIM + c);
    const float4* xp = reinterpret_cast<const float4*>(x + (size_t)r * DIM + c);
    float4 e0 = ep[0], e1 = ep[1];
    float4 x0 = xp[0], x1 = xp[1];
    float* q = quant + (size_t)r * DIM + c;   // base misaligned by 1 float
    q[0] = e0.x; q[1] = e0.y; q[2] = e0.z; q[3] = e0.w;
    q[4] = e1.x; q[5] = e1.y; q[6] = e1.z; q[7] = e1.w;
    float d0 = e0.x - x0.x, d1 = e0.y - x0.y, d2 = e0.z - x0.z, d3 = e0.w - x0.w;
    float d4 = e1.x - x1.x, d5 = e1.y - x1.y, d6 = e1.z - x1.z, d7 = e1.w - x1.w;
    float acc = fmaf(d0, d0, fmaf(d1, d1, fmaf(d2, d2, d3 * d3)))
              + fmaf(d4, d4, fmaf(d5, d5, fmaf(d6, d6, d7 * d7)));
    #pragma unroll
    for (int off = 32; off > 0; off >>= 1) acc += __shfl_down(acc, off, 64);

    __shared__ float sacc[4];
    if ((threadIdx.x & 63) == 0) sacc[threadIdx.x >> 6] = acc;
    __syncthreads();
    if (threadIdx.x == 0)
        partials[blockIdx.x] =
            (double)sacc[0] + (double)sacc[1] + (double)sacc[2] + (double)sacc[3];
}

// ---- final loss: sum 4096 block partials in one block ---------------------
__global__ __launch_bounds__(256) void vq_loss(
        const double* __restrict__ partials, float* __restrict__ out) {
    double s = 0.0;
    #pragma unroll
    for (int i = 0; i < 16; ++i) s += partials[threadIdx.x + i * 256];
    #pragma unroll
    for (int off = 32; off > 0; off >>= 1) s += __shfl_down(s, off, 64);
    __shared__ double sd[4];
    if ((threadIdx.x & 63) == 0) sd[threadIdx.x >> 6] = s;
    __syncthreads();
    if (threadIdx.x == 0)
        out[0] = (float)((sd[0] + sd[1] + sd[2] + sd[3]) * (1.25 / 8388608.0));
}

extern "C" void kernel_launch(void* const* d_in, const int* in_sizes, int n_in,
                              void* d_out, int out_size, void* d_ws, size_t ws_size,
                              hipStream_t stream) {
    const float* x   = (const float*)d_in[0];   // [32,2048,128] f32
    const float* emb = (const float*)d_in[1];   // [1024,128] f32

    float* out      = (float*)d_out;
    float* loss_out = out;
    float* quant    = out + 1;                        // [8388608]
    float* idx_out  = out + 1 + (size_t)NROWS * DIM;  // [65536] as float

    // bf16 X splits staged inside the (later overwritten) quant region.
    unsigned short* xh = (unsigned short*)((char*)d_out + 16);
    unsigned short* xm = xh + (size_t)NROWS * DIM;    // 16 MB each

    char* ws = (char*)d_ws;
    int*    fb_cnt   = (int*)(ws + 8);                  // [8,12)
    float*  enorm    = (float*)(ws + 1024);             // 4 KB
    float*  neg_half = (float*)(ws + 5120);             // 4 KB
    int*    fb_rows  = (int*)(ws + 16384);              // 256 KB
    int*    bestk    = (int*)(ws + 278528);             // 256 KB
    unsigned short* eh = (unsigned short*)(ws + 557056); // 256 KB
    unsigned short* em = (unsigned short*)(ws + 819200); // 256 KB
    double* partials = (double*)(ws + 1081344);          // 32 KB (4096 doubles)

    hipMemsetAsync(ws, 0, 16, stream);
    split_x<<<4096, 256, 0, stream>>>(x, xh, xm);
    split_e<<<64, 256, 0, stream>>>(emb, eh, em);
    vq_norms<<<4, 256, 0, stream>>>(emb, enorm, neg_half);
    vq_mfma<<<512, 256, 0, stream>>>(xh, xm, eh, em, neg_half,
                                     bestk, idx_out, fb_cnt, fb_rows);
    vq_fallback<<<256, 256, 0, stream>>>(x, emb, enorm, fb_cnt, fb_rows,
                                         bestk, idx_out);
    vq_gather<<<4096, 256, 0, stream>>>(x, emb, bestk, quant, partials);
    vq_loss<<<1, 256, 0, stream>>>(partials, loss_out);
}

// Round 5
// 176.055 us; speedup vs baseline: 3.6554x; 1.4540x over previous
//
#include <hip/hip_runtime.h>

#define NROWS 65536
#define KC    1024
#define DIM   128
#define W_DIST 5e-5f

typedef short  bf16x8 __attribute__((ext_vector_type(8)));
typedef float  f32x4  __attribute__((ext_vector_type(4)));

__device__ __forceinline__ unsigned short f2bf_rne(float f) {
    unsigned int u = __float_as_uint(f);
    u += 0x7FFFu + ((u >> 16) & 1u);
    return (unsigned short)(u >> 16);
}
__device__ __forceinline__ float bf2f(unsigned short h) {
    return __uint_as_float(((unsigned int)h) << 16);
}

// numpy pairwise sum-of-squares for n=128 (8 stride-8 accumulators, tree combine)
__device__ __forceinline__ float np_sumsq_128(const float* v) {
    float r[8];
    #pragma unroll
    for (int j = 0; j < 8; ++j) r[j] = __fmul_rn(v[j], v[j]);
    #pragma unroll
    for (int i = 1; i < 16; ++i)
        #pragma unroll
        for (int j = 0; j < 8; ++j)
            r[j] = __fadd_rn(r[j], __fmul_rn(v[i * 8 + j], v[i * 8 + j]));
    return __fadd_rn(__fadd_rn(__fadd_rn(r[0], r[1]), __fadd_rn(r[2], r[3])),
                     __fadd_rn(__fadd_rn(r[4], r[5]), __fadd_rn(r[6], r[7])));
}

// ---- split x into bf16 hi/mid: 8 elems per thread --------------------------
__global__ __launch_bounds__(256) void split_x(const float* __restrict__ x,
        unsigned short* __restrict__ xh, unsigned short* __restrict__ xm) {
    const int t = blockIdx.x * 256 + threadIdx.x;   // 1048576 threads
    const float4* p = reinterpret_cast<const float4*>(x) + (size_t)t * 2;
    float4 a = p[0], b = p[1];
    float f[8] = {a.x, a.y, a.z, a.w, b.x, b.y, b.z, b.w};
    unsigned int h[8], m[8];
    #pragma unroll
    for (int i = 0; i < 8; ++i) {
        unsigned short hh = f2bf_rne(f[i]);
        h[i] = hh;
        m[i] = f2bf_rne(f[i] - bf2f(hh));
    }
    uint4 vh = {h[0] | (h[1] << 16), h[2] | (h[3] << 16),
                h[4] | (h[5] << 16), h[6] | (h[7] << 16)};
    uint4 vm = {m[0] | (m[1] << 16), m[2] | (m[3] << 16),
                m[4] | (m[5] << 16), m[6] | (m[7] << 16)};
    *reinterpret_cast<uint4*>(xh + (size_t)t * 8) = vh;
    *reinterpret_cast<uint4*>(xm + (size_t)t * 8) = vm;
}

// ---- split codebook into bf16 hi/mid -------------------------------------
__global__ __launch_bounds__(256) void split_e(const float* __restrict__ emb,
        unsigned short* __restrict__ eh, unsigned short* __restrict__ em) {
    const int t = blockIdx.x * 256 + threadIdx.x;   // 16384 threads
    const float4* p = reinterpret_cast<const float4*>(emb) + (size_t)t * 2;
    float4 a = p[0], b = p[1];
    float f[8] = {a.x, a.y, a.z, a.w, b.x, b.y, b.z, b.w};
    unsigned int h[8], m[8];
    #pragma unroll
    for (int i = 0; i < 8; ++i) {
        unsigned short hh = f2bf_rne(f[i]);
        h[i] = hh;
        m[i] = f2bf_rne(f[i] - bf2f(hh));
    }
    uint4 vh = {h[0] | (h[1] << 16), h[2] | (h[3] << 16),
                h[4] | (h[5] << 16), h[6] | (h[7] << 16)};
    uint4 vm = {m[0] | (m[1] << 16), m[2] | (m[3] << 16),
                m[4] | (m[5] << 16), m[6] | (m[7] << 16)};
    *reinterpret_cast<uint4*>(eh + (size_t)t * 8) = vh;
    *reinterpret_cast<uint4*>(em + (size_t)t * 8) = vm;
}

// ---- codebook norms: numpy-pairwise exact ---------------------------------
__global__ __launch_bounds__(256) void vq_norms(const float* __restrict__ emb,
        float* __restrict__ enorm) {
    const int k = blockIdx.x * 256 + threadIdx.x;
    if (k >= KC) return;
    float v[DIM];
    const float4* e = reinterpret_cast<const float4*>(emb + (size_t)k * DIM);
    #pragma unroll
    for (int i = 0; i < 32; ++i) {
        float4 t = e[i];
        v[i * 4 + 0] = t.x; v[i * 4 + 1] = t.y;
        v[i * 4 + 2] = t.z; v[i * 4 + 3] = t.w;
    }
    enorm[k] = np_sumsq_128(v);
}

// ---- main MFMA distance + top-2 kernel ------------------------------------
// Block = 4 waves x 32 rows = 128 rows. E-tile (16 k-rows, hi+mid = 8 KB)
// double-buffered in LDS, shared by the 4 waves. LDS layout is unit-major
// [kc][lg][row] so each wave's ds_read_b128 is 1 KB contiguous (no conflicts).
__global__ __launch_bounds__(256, 2) void vq_mfma(
        const unsigned short* __restrict__ xh, const unsigned short* __restrict__ xm,
        const unsigned short* __restrict__ eh, const unsigned short* __restrict__ em,
        const float* __restrict__ enorm,
        int* __restrict__ bestk, float* __restrict__ idx_out,
        int* __restrict__ fb_cnt, int* __restrict__ fb_rows) {
    const int tid  = threadIdx.x;
    const int lane = tid & 63;
    const int wid  = tid >> 6;
    const int rtile = blockIdx.x * 128 + wid * 32;   // 32 rows per wave
    const int lr = lane & 15;
    const int lg = lane >> 4;

    __shared__ short ldsE[2][2][2048];   // [dbuf][hi/mid][16x128 bf16] = 16 KB

    // staging decode: thread t owns 16B unit u=t: kc=t>>6, lgw=(t>>4)&3, row=t&15
    const int s_row = tid & 15;
    const int s_col = ((tid >> 6) * 32) + (((tid >> 4) & 3) * 8);
    const int s_ldoff = tid * 8;                       // in shorts
    const unsigned short* geh = eh + (size_t)s_row * DIM + s_col;
    const unsigned short* gem = em + (size_t)s_row * DIM + s_col;

    // X fragments resident for whole kernel: [nt][kc]
    bf16x8 fxh[2][4], fxm[2][4];
    #pragma unroll
    for (int nt = 0; nt < 2; ++nt) {
        const unsigned short* ph = xh + (size_t)(rtile + nt * 16 + lr) * DIM + lg * 8;
        const unsigned short* pm = xm + (size_t)(rtile + nt * 16 + lr) * DIM + lg * 8;
        #pragma unroll
        for (int kc = 0; kc < 4; ++kc) {
            fxh[nt][kc] = *reinterpret_cast<const bf16x8*>(ph + kc * 32);
            fxm[nt][kc] = *reinterpret_cast<const bf16x8*>(pm + kc * 32);
        }
    }
    // pin fragments in VGPRs: asm-defined values can't be rematerialized
    #pragma unroll
    for (int nt = 0; nt < 2; ++nt)
        #pragma unroll
        for (int kc = 0; kc < 4; ++kc)
            asm volatile("" : "+v"(fxh[nt][kc]), "+v"(fxm[nt][kc]));

    // prologue: stage tile m=0
    {
        bf16x8 vh = *reinterpret_cast<const bf16x8*>(geh);
        bf16x8 vm = *reinterpret_cast<const bf16x8*>(gem);
        *reinterpret_cast<bf16x8*>(&ldsE[0][0][s_ldoff]) = vh;
        *reinterpret_cast<bf16x8*>(&ldsE[0][1][s_ldoff]) = vm;
    }
    __syncthreads();

    float m1_0 = 1e30f, m2_0 = 1e30f; int k1_0 = 0;
    float m1_1 = 1e30f, m2_1 = 1e30f; int k1_1 = 0;

    for (int m = 0; m < 64; ++m) {
        const int cur = m & 1, nxt = cur ^ 1;
        // T14: issue next E-tile global loads before compute (hides L2 latency)
        bf16x8 nh, nm;
        if (m < 63) {
            nh = *reinterpret_cast<const bf16x8*>(geh + (m + 1) * 2048);
            nm = *reinterpret_cast<const bf16x8*>(gem + (m + 1) * 2048);
        }
        const int m0 = m * 16;
        const f32x4 nrm = *reinterpret_cast<const f32x4*>(enorm + m0 + lg * 4);
        // 6 independent accumulator chains: (hh, h*m, m*h) x 2 n-tiles
        f32x4 A0 = {0.f, 0.f, 0.f, 0.f}, A1 = {0.f, 0.f, 0.f, 0.f};
        f32x4 B0 = {0.f, 0.f, 0.f, 0.f}, B1 = {0.f, 0.f, 0.f, 0.f};
        f32x4 C0 = {0.f, 0.f, 0.f, 0.f}, C1 = {0.f, 0.f, 0.f, 0.f};
        #pragma unroll
        for (int kc = 0; kc < 4; ++kc) {
            const int u = ((kc * 4 + lg) * 16 + lr) * 8;
            bf16x8 feh = *reinterpret_cast<const bf16x8*>(&ldsE[cur][0][u]);
            bf16x8 fem = *reinterpret_cast<const bf16x8*>(&ldsE[cur][1][u]);
            A0 = __builtin_amdgcn_mfma_f32_16x16x32_bf16(feh, fxh[0][kc], A0, 0, 0, 0);
            A1 = __builtin_amdgcn_mfma_f32_16x16x32_bf16(feh, fxh[1][kc], A1, 0, 0, 0);
            B0 = __builtin_amdgcn_mfma_f32_16x16x32_bf16(feh, fxm[0][kc], B0, 0, 0, 0);
            B1 = __builtin_amdgcn_mfma_f32_16x16x32_bf16(feh, fxm[1][kc], B1, 0, 0, 0);
            C0 = __builtin_amdgcn_mfma_f32_16x16x32_bf16(fem, fxh[0][kc], C0, 0, 0, 0);
            C1 = __builtin_amdgcn_mfma_f32_16x16x32_bf16(fem, fxh[1][kc], C1, 0, 0, 0);
        }
        const int kbase = m0 + lg * 4;
        #pragma unroll
        for (int r = 0; r < 4; ++r) {
            {
                float s = (A0[r] + B0[r]) + C0[r];
                float v = fmaf(-2.0f, s, nrm[r]);
                int kk = kbase + r;
                bool lt = v < m1_0;
                m2_0 = lt ? m1_0 : fminf(m2_0, v);
                k1_0 = lt ? kk : k1_0;
                m1_0 = lt ? v : m1_0;
            }
            {
                float s = (A1[r] + B1[r]) + C1[r];
                float v = fmaf(-2.0f, s, nrm[r]);
                int kk = kbase + r;
                bool lt = v < m1_1;
                m2_1 = lt ? m1_1 : fminf(m2_1, v);
                k1_1 = lt ? kk : k1_1;
                m1_1 = lt ? v : m1_1;
            }
        }
        if (m < 63) {   // ds_write next tile (loads drained via implicit vmcnt)
            *reinterpret_cast<bf16x8*>(&ldsE[nxt][0][s_ldoff]) = nh;
            *reinterpret_cast<bf16x8*>(&ldsE[nxt][1][s_ldoff]) = nm;
        }
        __syncthreads();
    }

    // merge the 4 lane-groups (each saw a disjoint k-subset) per row
    #pragma unroll
    for (int off = 16; off <= 32; off <<= 1) {
        {   float om1 = __shfl_xor(m1_0, off, 64);
            float om2 = __shfl_xor(m2_0, off, 64);
            int   ok1 = __shfl_xor(k1_0, off, 64);
            float hi = fmaxf(m1_0, om1);
            m2_0 = fminf(fminf(m2_0, om2), hi);
            bool take = om1 < m1_0;
            k1_0 = take ? ok1 : k1_0;
            m1_0 = fminf(m1_0, om1); }
        {   float om1 = __shfl_xor(m1_1, off, 64);
            float om2 = __shfl_xor(m2_1, off, 64);
            int   ok1 = __shfl_xor(k1_1, off, 64);
            float hi = fmaxf(m1_1, om1);
            m2_1 = fminf(fminf(m2_1, om2), hi);
            bool take = om1 < m1_1;
            k1_1 = take ? ok1 : k1_1;
            m1_1 = fminf(m1_1, om1); }
    }

    if (lane < 16) {
        #pragma unroll
        for (int nt = 0; nt < 2; ++nt) {
            const int row = rtile + nt * 16 + lane;
            float m1 = nt ? m1_1 : m1_0;
            float m2 = nt ? m2_1 : m2_0;
            int   k1 = nt ? k1_1 : k1_0;
            if (m2 - m1 < W_DIST) {          // ambiguous under rounding: refine
                int slot = atomicAdd(fb_cnt, 1);
                fb_rows[slot] = row;
            } else {
                bestk[row] = k1;
                idx_out[row] = (float)k1;
            }
        }
    }
}

// ---- exact fallback: one wave per ambiguous row, bit-replicated formula ----
__global__ __launch_bounds__(256, 2) void vq_fallback(
        const float* __restrict__ x, const float* __restrict__ emb,
        const float* __restrict__ enorm,
        const int* __restrict__ fb_cnt, const int* __restrict__ fb_rows,
        int* __restrict__ bestk, float* __restrict__ idx_out) {
    const int lane = threadIdx.x & 63;
    const int wgid = blockIdx.x * 4 + (threadIdx.x >> 6);
    const int nw = gridDim.x * 4;
    const int n = *fb_cnt;
    for (int i = wgid; i < n; i += nw) {
        const int row = fb_rows[i];
        const float4* xr = reinterpret_cast<const float4*>(x + (size_t)row * DIM);
        float r8[8];
        {
            float4 a = xr[0], b = xr[1];
            r8[0] = __fmul_rn(a.x, a.x); r8[1] = __fmul_rn(a.y, a.y);
            r8[2] = __fmul_rn(a.z, a.z); r8[3] = __fmul_rn(a.w, a.w);
            r8[4] = __fmul_rn(b.x, b.x); r8[5] = __fmul_rn(b.y, b.y);
            r8[6] = __fmul_rn(b.z, b.z); r8[7] = __fmul_rn(b.w, b.w);
            for (int q = 1; q < 16; ++q) {
                float4 c = xr[2 * q], d = xr[2 * q + 1];
                r8[0] = __fadd_rn(r8[0], __fmul_rn(c.x, c.x));
                r8[1] = __fadd_rn(r8[1], __fmul_rn(c.y, c.y));
                r8[2] = __fadd_rn(r8[2], __fmul_rn(c.z, c.z));
                r8[3] = __fadd_rn(r8[3], __fmul_rn(c.w, c.w));
                r8[4] = __fadd_rn(r8[4], __fmul_rn(d.x, d.x));
                r8[5] = __fadd_rn(r8[5], __fmul_rn(d.y, d.y));
                r8[6] = __fadd_rn(r8[6], __fmul_rn(d.z, d.z));
                r8[7] = __fadd_rn(r8[7], __fmul_rn(d.w, d.w));
            }
        }
        float xnorm = __fadd_rn(
            __fadd_rn(__fadd_rn(r8[0], r8[1]), __fadd_rn(r8[2], r8[3])),
            __fadd_rn(__fadd_rn(r8[4], r8[5]), __fadd_rn(r8[6], r8[7])));

        float bv = 3.402823466e38f; int bk = 0;
        for (int j = 0; j < 16; ++j) {
            const int k = lane + j * 64;     // ascending k per lane
            const float4* er = reinterpret_cast<const float4*>(emb + (size_t)k * DIM);
            float d0 = 0.f, d1 = 0.f, d2 = 0.f, d3 = 0.f;
            #pragma unroll
            for (int q = 0; q < 32; ++q) {
                float4 ev = er[q]; float4 xv = xr[q];
                d0 = fmaf(xv.x, ev.x, d0);
                d1 = fmaf(xv.y, ev.y, d1);
                d2 = fmaf(xv.z, ev.z, d2);
                d3 = fmaf(xv.w, ev.w, d3);
            }
            float dot = __fadd_rn(__fadd_rn(d0, d1), __fadd_rn(d2, d3));
            float s = __fsub_rn(__fadd_rn(xnorm, enorm[k]), __fmul_rn(2.0f, dot));
            if (s < bv) { bv = s; bk = k; }
        }
        #pragma unroll
        for (int off = 1; off < 64; off <<= 1) {
            float ov = __shfl_xor(bv, off, 64);
            int   ok = __shfl_xor(bk, off, 64);
            bool take = (ov < bv) || (ov == bv && ok < bk);
            bv = take ? ov : bv;
            bk = take ? ok : bk;
        }
        if (lane == 0) { bestk[row] = bk; idx_out[row] = (float)bk; }
    }
}

// ---- gather quantized rows + per-block loss partials (no atomics) ---------
__global__ __launch_bounds__(256) void vq_gather(
        const float* __restrict__ x, const float* __restrict__ emb,
        const int* __restrict__ bestk, float* __restrict__ quant,
        double* __restrict__ partials) {
    const int t = blockIdx.x * 256 + threadIdx.x;   // 1048576 threads, 8 elems
    const int r = t >> 4;
    const int c = (t & 15) * 8;
    const int bk = bestk[r];
    const float4* ep = reinterpret_cast<const float4*>(emb + (size_t)bk * DIM + c);
    const float4* xp = reinterpret_cast<const float4*>(x + (size_t)r * DIM + c);
    float4 e0 = ep[0], e1 = ep[1];
    float4 x0 = xp[0], x1 = xp[1];
    float* q = quant + (size_t)r * DIM + c;   // base misaligned by 1 float
    q[0] = e0.x; q[1] = e0.y; q[2] = e0.z; q[3] = e0.w;
    q[4] = e1.x; q[5] = e1.y; q[6] = e1.z; q[7] = e1.w;
    float d0 = e0.x - x0.x, d1 = e0.y - x0.y, d2 = e0.z - x0.z, d3 = e0.w - x0.w;
    float d4 = e1.x - x1.x, d5 = e1.y - x1.y, d6 = e1.z - x1.z, d7 = e1.w - x1.w;
    float acc = fmaf(d0, d0, fmaf(d1, d1, fmaf(d2, d2, d3 * d3)))
              + fmaf(d4, d4, fmaf(d5, d5, fmaf(d6, d6, d7 * d7)));
    #pragma unroll
    for (int off = 32; off > 0; off >>= 1) acc += __shfl_down(acc, off, 64);

    __shared__ float sacc[4];
    if ((threadIdx.x & 63) == 0) sacc[threadIdx.x >> 6] = acc;
    __syncthreads();
    if (threadIdx.x == 0)
        partials[blockIdx.x] =
            (double)sacc[0] + (double)sacc[1] + (double)sacc[2] + (double)sacc[3];
}

// ---- final loss: sum 4096 block partials in one block ---------------------
__global__ __launch_bounds__(256) void vq_loss(
        const double* __restrict__ partials, float* __restrict__ out) {
    double s = 0.0;
    #pragma unroll
    for (int i = 0; i < 16; ++i) s += partials[threadIdx.x + i * 256];
    #pragma unroll
    for (int off = 32; off > 0; off >>= 1) s += __shfl_down(s, off, 64);
    __shared__ double sd[4];
    if ((threadIdx.x & 63) == 0) sd[threadIdx.x >> 6] = s;
    __syncthreads();
    if (threadIdx.x == 0)
        out[0] = (float)((sd[0] + sd[1] + sd[2] + sd[3]) * (1.25 / 8388608.0));
}

extern "C" void kernel_launch(void* const* d_in, const int* in_sizes, int n_in,
                              void* d_out, int out_size, void* d_ws, size_t ws_size,
                              hipStream_t stream) {
    const float* x   = (const float*)d_in[0];   // [32,2048,128] f32
    const float* emb = (const float*)d_in[1];   // [1024,128] f32

    float* out      = (float*)d_out;
    float* loss_out = out;
    float* quant    = out + 1;                        // [8388608]
    float* idx_out  = out + 1 + (size_t)NROWS * DIM;  // [65536] as float

    // bf16 X splits staged inside the (later overwritten) quant region.
    unsigned short* xh = (unsigned short*)((char*)d_out + 16);
    unsigned short* xm = xh + (size_t)NROWS * DIM;    // 16 MB each

    char* ws = (char*)d_ws;
    int*    fb_cnt   = (int*)(ws + 8);                  // [8,12)
    float*  enorm    = (float*)(ws + 1024);             // 4 KB
    int*    fb_rows  = (int*)(ws + 16384);              // 256 KB
    int*    bestk    = (int*)(ws + 278528);             // 256 KB
    unsigned short* eh = (unsigned short*)(ws + 557056); // 256 KB
    unsigned short* em = (unsigned short*)(ws + 819200); // 256 KB
    double* partials = (double*)(ws + 1081344);          // 32 KB (4096 doubles)

    hipMemsetAsync(ws, 0, 16, stream);
    split_x<<<4096, 256, 0, stream>>>(x, xh, xm);
    split_e<<<64, 256, 0, stream>>>(emb, eh, em);
    vq_norms<<<4, 256, 0, stream>>>(emb, enorm);
    vq_mfma<<<512, 256, 0, stream>>>(xh, xm, eh, em, enorm,
                                     bestk, idx_out, fb_cnt, fb_rows);
    vq_fallback<<<256, 256, 0, stream>>>(x, emb, enorm, fb_cnt, fb_rows,
                                         bestk, idx_out);
    vq_gather<<<4096, 256, 0, stream>>>(x, emb, bestk, quant, partials);
    vq_loss<<<1, 256, 0, stream>>>(partials, loss_out);
}

// Round 6
// 157.350 us; speedup vs baseline: 4.0900x; 1.1189x over previous
//
#include <hip/hip_runtime.h>

#define NROWS 65536
#define KC    1024
#define DIM   128
#define W_DIST 5e-5f

typedef short  bf16x8 __attribute__((ext_vector_type(8)));
typedef float  f32x4  __attribute__((ext_vector_type(4)));

__device__ __forceinline__ unsigned short f2bf_rne(float f) {
    unsigned int u = __float_as_uint(f);
    u += 0x7FFFu + ((u >> 16) & 1u);
    return (unsigned short)(u >> 16);
}
__device__ __forceinline__ float bf2f(unsigned short h) {
    return __uint_as_float(((unsigned int)h) << 16);
}

// numpy pairwise sum-of-squares for n=128 (8 stride-8 accumulators, tree combine)
__device__ __forceinline__ float np_sumsq_128(const float* v) {
    float r[8];
    #pragma unroll
    for (int j = 0; j < 8; ++j) r[j] = __fmul_rn(v[j], v[j]);
    #pragma unroll
    for (int i = 1; i < 16; ++i)
        #pragma unroll
        for (int j = 0; j < 8; ++j)
            r[j] = __fadd_rn(r[j], __fmul_rn(v[i * 8 + j], v[i * 8 + j]));
    return __fadd_rn(__fadd_rn(__fadd_rn(r[0], r[1]), __fadd_rn(r[2], r[3])),
                     __fadd_rn(__fadd_rn(r[4], r[5]), __fadd_rn(r[6], r[7])));
}

// ---- codebook prep: exact norms + bf16 hi/mid split (fused) ---------------
__global__ __launch_bounds__(256) void vq_prep(const float* __restrict__ emb,
        float* __restrict__ enorm,
        unsigned short* __restrict__ eh, unsigned short* __restrict__ em) {
    const int k = blockIdx.x * 256 + threadIdx.x;   // one thread per codebook row
    if (k >= KC) return;
    float v[DIM];
    const float4* e = reinterpret_cast<const float4*>(emb + (size_t)k * DIM);
    #pragma unroll
    for (int i = 0; i < 32; ++i) {
        float4 t = e[i];
        v[i * 4 + 0] = t.x; v[i * 4 + 1] = t.y;
        v[i * 4 + 2] = t.z; v[i * 4 + 3] = t.w;
    }
    enorm[k] = np_sumsq_128(v);
    unsigned short* ph = eh + (size_t)k * DIM;
    unsigned short* pm = em + (size_t)k * DIM;
    #pragma unroll
    for (int i = 0; i < 16; ++i) {
        unsigned int h[8], m[8];
        #pragma unroll
        for (int j = 0; j < 8; ++j) {
            float f = v[i * 8 + j];
            unsigned short hh = f2bf_rne(f);
            h[j] = hh;
            m[j] = f2bf_rne(f - bf2f(hh));
        }
        uint4 vh = {h[0] | (h[1] << 16), h[2] | (h[3] << 16),
                    h[4] | (h[5] << 16), h[6] | (h[7] << 16)};
        uint4 vm = {m[0] | (m[1] << 16), m[2] | (m[3] << 16),
                    m[4] | (m[5] << 16), m[6] | (m[7] << 16)};
        *reinterpret_cast<uint4*>(ph + i * 8) = vh;
        *reinterpret_cast<uint4*>(pm + i * 8) = vm;
    }
}

// ---- main MFMA distance + top-2 kernel ------------------------------------
// Block = 4 waves x 32 rows = 128 rows. X loaded as f32 and split to bf16
// hi/mid in-register (no split_x pass). E-tile (16 k-rows, hi+mid = 8 KB)
// staged through a 4-buffer LDS rotation with loads issued one full
// iteration before their ds_write (T14 async-stage split).
__global__ __launch_bounds__(256, 2) void vq_mfma(
        const float* __restrict__ x,
        const unsigned short* __restrict__ eh, const unsigned short* __restrict__ em,
        const float* __restrict__ enorm,
        int* __restrict__ bestk, float* __restrict__ idx_out,
        int* __restrict__ fb_cnt, int* __restrict__ fb_rows) {
    const int tid  = threadIdx.x;
    const int lane = tid & 63;
    const int wid  = tid >> 6;
    const int rtile = blockIdx.x * 128 + wid * 32;   // 32 rows per wave
    const int lr = lane & 15;
    const int lg = lane >> 4;

    __shared__ short ldsE[4][2][2048];   // [buf][hi/mid][16x128 bf16] = 32 KB

    // staging decode: thread t owns 16B unit t: kc=t>>6, lgw=(t>>4)&3, row=t&15
    const int s_row = tid & 15;
    const int s_col = ((tid >> 6) * 32) + (((tid >> 4) & 3) * 8);
    const int s_ldoff = tid * 8;                       // in shorts
    const unsigned short* geh = eh + (size_t)s_row * DIM + s_col;
    const unsigned short* gem = em + (size_t)s_row * DIM + s_col;

    // X fragments: load f32, split to bf16 hi/mid in-register
    bf16x8 fxh[2][4], fxm[2][4];
    #pragma unroll
    for (int nt = 0; nt < 2; ++nt) {
        const float* px = x + (size_t)(rtile + nt * 16 + lr) * DIM + lg * 8;
        #pragma unroll
        for (int kc = 0; kc < 4; ++kc) {
            float4 a = *reinterpret_cast<const float4*>(px + kc * 32);
            float4 b = *reinterpret_cast<const float4*>(px + kc * 32 + 4);
            float f[8] = {a.x, a.y, a.z, a.w, b.x, b.y, b.z, b.w};
            bf16x8 vh, vm;
            #pragma unroll
            for (int j = 0; j < 8; ++j) {
                unsigned short hh = f2bf_rne(f[j]);
                vh[j] = (short)hh;
                vm[j] = (short)f2bf_rne(f[j] - bf2f(hh));
            }
            fxh[nt][kc] = vh;
            fxm[nt][kc] = vm;
        }
    }
    // pin fragments in VGPRs (prevent rematerialization)
    #pragma unroll
    for (int nt = 0; nt < 2; ++nt)
        #pragma unroll
        for (int kc = 0; kc < 4; ++kc)
            asm volatile("" : "+v"(fxh[nt][kc]), "+v"(fxm[nt][kc]));

    // prologue: stage tile 0 into buf0; issue tile 1 into reg set 1
    bf16x8 rpH[2], rpM[2];
    {
        bf16x8 vh = *reinterpret_cast<const bf16x8*>(geh);
        bf16x8 vm = *reinterpret_cast<const bf16x8*>(gem);
        *reinterpret_cast<bf16x8*>(&ldsE[0][0][s_ldoff]) = vh;
        *reinterpret_cast<bf16x8*>(&ldsE[0][1][s_ldoff]) = vm;
        rpH[1] = *reinterpret_cast<const bf16x8*>(geh + 2048);
        rpM[1] = *reinterpret_cast<const bf16x8*>(gem + 2048);
    }
    __syncthreads();

    float m1_0 = 1e30f, m2_0 = 1e30f; int k1_0 = 0;
    float m1_1 = 1e30f, m2_1 = 1e30f; int k1_1 = 0;

    for (int mb = 0; mb < 64; mb += 4) {
        #pragma unroll
        for (int u = 0; u < 4; ++u) {
            const int m = mb + u;          // buffer index = m & 3 = u
            const int wr = (u + 1) & 3;
            // ds_write tile m+1 (its loads were issued one iteration ago)
            if (m < 63) {
                *reinterpret_cast<bf16x8*>(&ldsE[wr][0][s_ldoff]) = rpH[(u + 1) & 1];
                *reinterpret_cast<bf16x8*>(&ldsE[wr][1][s_ldoff]) = rpM[(u + 1) & 1];
            }
            // issue tile m+2 loads (consumed at iter m+1's ds_write)
            if (m < 62) {
                rpH[u & 1] = *reinterpret_cast<const bf16x8*>(geh + (m + 2) * 2048);
                rpM[u & 1] = *reinterpret_cast<const bf16x8*>(gem + (m + 2) * 2048);
            }
            const int m0 = m * 16;
            const f32x4 nrm = *reinterpret_cast<const f32x4*>(enorm + m0 + lg * 4);
            f32x4 A0 = {0.f, 0.f, 0.f, 0.f}, A1 = {0.f, 0.f, 0.f, 0.f};
            f32x4 B0 = {0.f, 0.f, 0.f, 0.f}, B1 = {0.f, 0.f, 0.f, 0.f};
            f32x4 C0 = {0.f, 0.f, 0.f, 0.f}, C1 = {0.f, 0.f, 0.f, 0.f};
            __builtin_amdgcn_s_setprio(1);
            #pragma unroll
            for (int kc = 0; kc < 4; ++kc) {
                const int off = ((kc * 4 + lg) * 16 + lr) * 8;
                bf16x8 feh = *reinterpret_cast<const bf16x8*>(&ldsE[u][0][off]);
                bf16x8 fem = *reinterpret_cast<const bf16x8*>(&ldsE[u][1][off]);
                A0 = __builtin_amdgcn_mfma_f32_16x16x32_bf16(feh, fxh[0][kc], A0, 0, 0, 0);
                A1 = __builtin_amdgcn_mfma_f32_16x16x32_bf16(feh, fxh[1][kc], A1, 0, 0, 0);
                B0 = __builtin_amdgcn_mfma_f32_16x16x32_bf16(feh, fxm[0][kc], B0, 0, 0, 0);
                B1 = __builtin_amdgcn_mfma_f32_16x16x32_bf16(feh, fxm[1][kc], B1, 0, 0, 0);
                C0 = __builtin_amdgcn_mfma_f32_16x16x32_bf16(fem, fxh[0][kc], C0, 0, 0, 0);
                C1 = __builtin_amdgcn_mfma_f32_16x16x32_bf16(fem, fxh[1][kc], C1, 0, 0, 0);
            }
            __builtin_amdgcn_s_setprio(0);
            const int kbase = m0 + lg * 4;
            #pragma unroll
            for (int r = 0; r < 4; ++r) {
                {
                    float s = (A0[r] + B0[r]) + C0[r];
                    float v = fmaf(-2.0f, s, nrm[r]);
                    int kk = kbase + r;
                    bool lt = v < m1_0;
                    m2_0 = lt ? m1_0 : fminf(m2_0, v);
                    k1_0 = lt ? kk : k1_0;
                    m1_0 = lt ? v : m1_0;
                }
                {
                    float s = (A1[r] + B1[r]) + C1[r];
                    float v = fmaf(-2.0f, s, nrm[r]);
                    int kk = kbase + r;
                    bool lt = v < m1_1;
                    m2_1 = lt ? m1_1 : fminf(m2_1, v);
                    k1_1 = lt ? kk : k1_1;
                    m1_1 = lt ? v : m1_1;
                }
            }
            __syncthreads();
        }
    }

    // merge the 4 lane-groups (each saw a disjoint k-subset) per row
    #pragma unroll
    for (int off = 16; off <= 32; off <<= 1) {
        {   float om1 = __shfl_xor(m1_0, off, 64);
            float om2 = __shfl_xor(m2_0, off, 64);
            int   ok1 = __shfl_xor(k1_0, off, 64);
            float hi = fmaxf(m1_0, om1);
            m2_0 = fminf(fminf(m2_0, om2), hi);
            bool take = om1 < m1_0;
            k1_0 = take ? ok1 : k1_0;
            m1_0 = fminf(m1_0, om1); }
        {   float om1 = __shfl_xor(m1_1, off, 64);
            float om2 = __shfl_xor(m2_1, off, 64);
            int   ok1 = __shfl_xor(k1_1, off, 64);
            float hi = fmaxf(m1_1, om1);
            m2_1 = fminf(fminf(m2_1, om2), hi);
            bool take = om1 < m1_1;
            k1_1 = take ? ok1 : k1_1;
            m1_1 = fminf(m1_1, om1); }
    }

    if (lane < 16) {
        #pragma unroll
        for (int nt = 0; nt < 2; ++nt) {
            const int row = rtile + nt * 16 + lane;
            float m1 = nt ? m1_1 : m1_0;
            float m2 = nt ? m2_1 : m2_0;
            int   k1 = nt ? k1_1 : k1_0;
            if (m2 - m1 < W_DIST) {          // ambiguous under rounding: refine
                int slot = atomicAdd(fb_cnt, 1);
                fb_rows[slot] = row;
            } else {
                bestk[row] = k1;
                idx_out[row] = (float)k1;
            }
        }
    }
}

// ---- exact fallback: one wave per ambiguous row, bit-replicated formula ----
__global__ __launch_bounds__(256, 2) void vq_fallback(
        const float* __restrict__ x, const float* __restrict__ emb,
        const float* __restrict__ enorm,
        const int* __restrict__ fb_cnt, const int* __restrict__ fb_rows,
        int* __restrict__ bestk, float* __restrict__ idx_out) {
    const int lane = threadIdx.x & 63;
    const int wgid = blockIdx.x * 4 + (threadIdx.x >> 6);
    const int nw = gridDim.x * 4;
    const int n = *fb_cnt;
    for (int i = wgid; i < n; i += nw) {
        const int row = fb_rows[i];
        const float4* xr = reinterpret_cast<const float4*>(x + (size_t)row * DIM);
        float r8[8];
        {
            float4 a = xr[0], b = xr[1];
            r8[0] = __fmul_rn(a.x, a.x); r8[1] = __fmul_rn(a.y, a.y);
            r8[2] = __fmul_rn(a.z, a.z); r8[3] = __fmul_rn(a.w, a.w);
            r8[4] = __fmul_rn(b.x, b.x); r8[5] = __fmul_rn(b.y, b.y);
            r8[6] = __fmul_rn(b.z, b.z); r8[7] = __fmul_rn(b.w, b.w);
            for (int q = 1; q < 16; ++q) {
                float4 c = xr[2 * q], d = xr[2 * q + 1];
                r8[0] = __fadd_rn(r8[0], __fmul_rn(c.x, c.x));
                r8[1] = __fadd_rn(r8[1], __fmul_rn(c.y, c.y));
                r8[2] = __fadd_rn(r8[2], __fmul_rn(c.z, c.z));
                r8[3] = __fadd_rn(r8[3], __fmul_rn(c.w, c.w));
                r8[4] = __fadd_rn(r8[4], __fmul_rn(d.x, d.x));
                r8[5] = __fadd_rn(r8[5], __fmul_rn(d.y, d.y));
                r8[6] = __fadd_rn(r8[6], __fmul_rn(d.z, d.z));
                r8[7] = __fadd_rn(r8[7], __fmul_rn(d.w, d.w));
            }
        }
        float xnorm = __fadd_rn(
            __fadd_rn(__fadd_rn(r8[0], r8[1]), __fadd_rn(r8[2], r8[3])),
            __fadd_rn(__fadd_rn(r8[4], r8[5]), __fadd_rn(r8[6], r8[7])));

        float bv = 3.402823466e38f; int bk = 0;
        for (int j = 0; j < 16; ++j) {
            const int k = lane + j * 64;     // ascending k per lane
            const float4* er = reinterpret_cast<const float4*>(emb + (size_t)k * DIM);
            float d0 = 0.f, d1 = 0.f, d2 = 0.f, d3 = 0.f;
            #pragma unroll
            for (int q = 0; q < 32; ++q) {
                float4 ev = er[q]; float4 xv = xr[q];
                d0 = fmaf(xv.x, ev.x, d0);
                d1 = fmaf(xv.y, ev.y, d1);
                d2 = fmaf(xv.z, ev.z, d2);
                d3 = fmaf(xv.w, ev.w, d3);
            }
            float dot = __fadd_rn(__fadd_rn(d0, d1), __fadd_rn(d2, d3));
            float s = __fsub_rn(__fadd_rn(xnorm, enorm[k]), __fmul_rn(2.0f, dot));
            if (s < bv) { bv = s; bk = k; }
        }
        #pragma unroll
        for (int off = 1; off < 64; off <<= 1) {
            float ov = __shfl_xor(bv, off, 64);
            int   ok = __shfl_xor(bk, off, 64);
            bool take = (ov < bv) || (ov == bv && ok < bk);
            bv = take ? ov : bv;
            bk = take ? ok : bk;
        }
        if (lane == 0) { bestk[row] = bk; idx_out[row] = (float)bk; }
    }
}

// ---- gather quantized rows + per-block loss partials (no atomics) ---------
__global__ __launch_bounds__(256) void vq_gather(
        const float* __restrict__ x, const float* __restrict__ emb,
        const int* __restrict__ bestk, float* __restrict__ quant,
        double* __restrict__ partials) {
    const int t = blockIdx.x * 256 + threadIdx.x;   // 1048576 threads, 8 elems
    const int r = t >> 4;
    const int c = (t & 15) * 8;
    const int bk = bestk[r];
    const float4* ep = reinterpret_cast<const float4*>(emb + (size_t)bk * DIM + c);
    const float4* xp = reinterpret_cast<const float4*>(x + (size_t)r * DIM + c);
    float4 e0 = ep[0], e1 = ep[1];
    float4 x0 = xp[0], x1 = xp[1];
    float* q = quant + (size_t)r * DIM + c;   // base misaligned by 1 float
    q[0] = e0.x; q[1] = e0.y; q[2] = e0.z; q[3] = e0.w;
    q[4] = e1.x; q[5] = e1.y; q[6] = e1.z; q[7] = e1.w;
    float d0 = e0.x - x0.x, d1 = e0.y - x0.y, d2 = e0.z - x0.z, d3 = e0.w - x0.w;
    float d4 = e1.x - x1.x, d5 = e1.y - x1.y, d6 = e1.z - x1.z, d7 = e1.w - x1.w;
    float acc = fmaf(d0, d0, fmaf(d1, d1, fmaf(d2, d2, d3 * d3)))
              + fmaf(d4, d4, fmaf(d5, d5, fmaf(d6, d6, d7 * d7)));
    #pragma unroll
    for (int off = 32; off > 0; off >>= 1) acc += __shfl_down(acc, off, 64);

    __shared__ float sacc[4];
    if ((threadIdx.x & 63) == 0) sacc[threadIdx.x >> 6] = acc;
    __syncthreads();
    if (threadIdx.x == 0)
        partials[blockIdx.x] =
            (double)sacc[0] + (double)sacc[1] + (double)sacc[2] + (double)sacc[3];
}

// ---- final loss: sum 4096 block partials in one block ---------------------
__global__ __launch_bounds__(256) void vq_loss(
        const double* __restrict__ partials, float* __restrict__ out) {
    double s = 0.0;
    #pragma unroll
    for (int i = 0; i < 16; ++i) s += partials[threadIdx.x + i * 256];
    #pragma unroll
    for (int off = 32; off > 0; off >>= 1) s += __shfl_down(s, off, 64);
    __shared__ double sd[4];
    if ((threadIdx.x & 63) == 0) sd[threadIdx.x >> 6] = s;
    __syncthreads();
    if (threadIdx.x == 0)
        out[0] = (float)((sd[0] + sd[1] + sd[2] + sd[3]) * (1.25 / 8388608.0));
}

extern "C" void kernel_launch(void* const* d_in, const int* in_sizes, int n_in,
                              void* d_out, int out_size, void* d_ws, size_t ws_size,
                              hipStream_t stream) {
    const float* x   = (const float*)d_in[0];   // [32,2048,128] f32
    const float* emb = (const float*)d_in[1];   // [1024,128] f32

    float* out      = (float*)d_out;
    float* loss_out = out;
    float* quant    = out + 1;                        // [8388608]
    float* idx_out  = out + 1 + (size_t)NROWS * DIM;  // [65536] as float

    char* ws = (char*)d_ws;
    int*    fb_cnt   = (int*)(ws + 8);                  // [8,12)
    float*  enorm    = (float*)(ws + 1024);             // 4 KB
    int*    fb_rows  = (int*)(ws + 16384);              // 256 KB
    int*    bestk    = (int*)(ws + 278528);             // 256 KB
    unsigned short* eh = (unsigned short*)(ws + 557056); // 256 KB
    unsigned short* em = (unsigned short*)(ws + 819200); // 256 KB
    double* partials = (double*)(ws + 1081344);          // 32 KB (4096 doubles)

    hipMemsetAsync(ws, 0, 16, stream);
    vq_prep<<<4, 256, 0, stream>>>(emb, enorm, eh, em);
    vq_mfma<<<512, 256, 0, stream>>>(x, eh, em, enorm,
                                     bestk, idx_out, fb_cnt, fb_rows);
    vq_fallback<<<256, 256, 0, stream>>>(x, emb, enorm, fb_cnt, fb_rows,
                                         bestk, idx_out);
    vq_gather<<<4096, 256, 0, stream>>>(x, emb, bestk, quant, partials);
    vq_loss<<<1, 256, 0, stream>>>(partials, loss_out);
}

// Round 7
// 154.788 us; speedup vs baseline: 4.1577x; 1.0166x over previous
//
#include <hip/hip_runtime.h>

#define NROWS 65536
#define KC    1024
#define DIM   128
#define W_DIST 5e-5f

typedef short  bf16x8 __attribute__((ext_vector_type(8)));
typedef float  f32x4  __attribute__((ext_vector_type(4)));

__device__ __forceinline__ unsigned short f2bf_rne(float f) {
    unsigned int u = __float_as_uint(f);
    u += 0x7FFFu + ((u >> 16) & 1u);
    return (unsigned short)(u >> 16);
}
__device__ __forceinline__ float bf2f(unsigned short h) {
    return __uint_as_float(((unsigned int)h) << 16);
}

// async global->LDS DMA, 16 B per lane; LDS dest = wave-uniform base + lane*16
__device__ __forceinline__ void gll16(const unsigned short* g, short* l) {
    __builtin_amdgcn_global_load_lds(
        (const __attribute__((address_space(1))) unsigned int*)g,
        (__attribute__((address_space(3))) unsigned int*)l,
        16, 0, 0);
}

template <int N>
__device__ __forceinline__ void vmwait() {
    if constexpr (N == 4)      asm volatile("s_waitcnt vmcnt(4)" ::: "memory");
    else if constexpr (N == 2) asm volatile("s_waitcnt vmcnt(2)" ::: "memory");
    else                       asm volatile("s_waitcnt vmcnt(0)" ::: "memory");
}

// numpy pairwise sum-of-squares for n=128 (8 stride-8 accumulators, tree combine)
__device__ __forceinline__ float np_sumsq_128(const float* v) {
    float r[8];
    #pragma unroll
    for (int j = 0; j < 8; ++j) r[j] = __fmul_rn(v[j], v[j]);
    #pragma unroll
    for (int i = 1; i < 16; ++i)
        #pragma unroll
        for (int j = 0; j < 8; ++j)
            r[j] = __fadd_rn(r[j], __fmul_rn(v[i * 8 + j], v[i * 8 + j]));
    return __fadd_rn(__fadd_rn(__fadd_rn(r[0], r[1]), __fadd_rn(r[2], r[3])),
                     __fadd_rn(__fadd_rn(r[4], r[5]), __fadd_rn(r[6], r[7])));
}

// ---- codebook prep: exact norms + bf16 hi/mid split (fused) ---------------
__global__ __launch_bounds__(256) void vq_prep(const float* __restrict__ emb,
        float* __restrict__ enorm,
        unsigned short* __restrict__ eh, unsigned short* __restrict__ em) {
    const int k = blockIdx.x * 256 + threadIdx.x;
    if (k >= KC) return;
    float v[DIM];
    const float4* e = reinterpret_cast<const float4*>(emb + (size_t)k * DIM);
    #pragma unroll
    for (int i = 0; i < 32; ++i) {
        float4 t = e[i];
        v[i * 4 + 0] = t.x; v[i * 4 + 1] = t.y;
        v[i * 4 + 2] = t.z; v[i * 4 + 3] = t.w;
    }
    enorm[k] = np_sumsq_128(v);
    unsigned short* ph = eh + (size_t)k * DIM;
    unsigned short* pm = em + (size_t)k * DIM;
    #pragma unroll
    for (int i = 0; i < 16; ++i) {
        unsigned int h[8], m[8];
        #pragma unroll
        for (int j = 0; j < 8; ++j) {
            float f = v[i * 8 + j];
            unsigned short hh = f2bf_rne(f);
            h[j] = hh;
            m[j] = f2bf_rne(f - bf2f(hh));
        }
        uint4 vh = {h[0] | (h[1] << 16), h[2] | (h[3] << 16),
                    h[4] | (h[5] << 16), h[6] | (h[7] << 16)};
        uint4 vm = {m[0] | (m[1] << 16), m[2] | (m[3] << 16),
                    m[4] | (m[5] << 16), m[6] | (m[7] << 16)};
        *reinterpret_cast<uint4*>(ph + i * 8) = vh;
        *reinterpret_cast<uint4*>(pm + i * 8) = vm;
    }
}

// ---- main MFMA distance + top-2 kernel ------------------------------------
// Block = 4 waves x 32 rows. E-tiles staged via global_load_lds (16B DMA, no
// VGPR roundtrip) into a 4-buffer LDS rotation, counted vmcnt(4): 3 tiles in
// flight across raw s_barriers. enorm lives in LDS so the K-loop has ZERO
// register-dest global loads (compiler inserts no vmcnt drains).
__global__ __launch_bounds__(256, 2) void vq_mfma(
        const float* __restrict__ x,
        const unsigned short* __restrict__ eh, const unsigned short* __restrict__ em,
        const float* __restrict__ enorm,
        int* __restrict__ bestk, float* __restrict__ idx_out,
        int* __restrict__ fb_cnt, int* __restrict__ fb_rows) {
    const int tid  = threadIdx.x;
    const int lane = tid & 63;
    const int wid  = tid >> 6;
    const int rtile = blockIdx.x * 128 + wid * 32;
    const int lr = lane & 15;
    const int lg = lane >> 4;

    __shared__ short ldsE[4][2][2048];   // [buf][hi/mid][16x128 bf16] = 32 KB
    __shared__ float s_enorm[KC];        // 4 KB

    // staging decode: thread t owns 16B unit t: row=t&15, col=(t>>6)*32+((t>>4)&3)*8
    const int s_row = tid & 15;
    const int s_col = ((tid >> 6) * 32) + (((tid >> 4) & 3) * 8);
    const unsigned short* geh = eh + (size_t)s_row * DIM + s_col;
    const unsigned short* gem = em + (size_t)s_row * DIM + s_col;

#define VQ_STAGE(T)                                                         \
    do {                                                                    \
        const int _b = (T) & 3;                                             \
        gll16(geh + (size_t)(T) * 2048, (short*)&ldsE[_b][0][0] + wid * 512); \
        gll16(gem + (size_t)(T) * 2048, (short*)&ldsE[_b][1][0] + wid * 512); \
    } while (0)

    // start DMA for tiles 0..2 immediately
    VQ_STAGE(0); VQ_STAGE(1); VQ_STAGE(2);

    // X fragments: load f32, split to bf16 hi/mid in-register
    bf16x8 fxh[2][4], fxm[2][4];
    #pragma unroll
    for (int nt = 0; nt < 2; ++nt) {
        const float* px = x + (size_t)(rtile + nt * 16 + lr) * DIM + lg * 8;
        #pragma unroll
        for (int kc = 0; kc < 4; ++kc) {
            float4 a = *reinterpret_cast<const float4*>(px + kc * 32);
            float4 b = *reinterpret_cast<const float4*>(px + kc * 32 + 4);
            float f[8] = {a.x, a.y, a.z, a.w, b.x, b.y, b.z, b.w};
            bf16x8 vh, vm;
            #pragma unroll
            for (int j = 0; j < 8; ++j) {
                unsigned short hh = f2bf_rne(f[j]);
                vh[j] = (short)hh;
                vm[j] = (short)f2bf_rne(f[j] - bf2f(hh));
            }
            fxh[nt][kc] = vh;
            fxm[nt][kc] = vm;
        }
    }
    #pragma unroll
    for (int nt = 0; nt < 2; ++nt)
        #pragma unroll
        for (int kc = 0; kc < 4; ++kc)
            asm volatile("" : "+v"(fxh[nt][kc]), "+v"(fxm[nt][kc]));

    // stage enorm into LDS (4 KB)
    *reinterpret_cast<float4*>(&s_enorm[tid * 4]) =
        *reinterpret_cast<const float4*>(&enorm[tid * 4]);
    __syncthreads();   // one full barrier before the pipelined loop

    float m1_0 = 1e30f, m2_0 = 1e30f; int k1_0 = 0;
    float m1_1 = 1e30f, m2_1 = 1e30f; int k1_1 = 0;

#define VQ_ITER(T, VMN, DO_ISSUE)                                            \
    do {                                                                     \
        vmwait<VMN>();                                                       \
        __builtin_amdgcn_s_barrier();                                        \
        asm volatile("" ::: "memory");                                       \
        const int _buf = (T) & 3;                                            \
        const int _m0 = (T) * 16;                                            \
        const f32x4 nrm = *reinterpret_cast<const f32x4*>(&s_enorm[_m0 + lg * 4]); \
        f32x4 A0 = {0.f,0.f,0.f,0.f}, A1 = {0.f,0.f,0.f,0.f};                \
        f32x4 D0 = {0.f,0.f,0.f,0.f}, D1 = {0.f,0.f,0.f,0.f};                \
        __builtin_amdgcn_s_setprio(1);                                       \
        _Pragma("unroll")                                                    \
        for (int kc = 0; kc < 4; ++kc) {                                     \
            const int off = ((kc * 4 + lg) * 16 + lr) * 8;                   \
            bf16x8 feh = *reinterpret_cast<const bf16x8*>(&ldsE[_buf][0][off]); \
            bf16x8 fem = *reinterpret_cast<const bf16x8*>(&ldsE[_buf][1][off]); \
            A0 = __builtin_amdgcn_mfma_f32_16x16x32_bf16(feh, fxh[0][kc], A0, 0, 0, 0); \
            A1 = __builtin_amdgcn_mfma_f32_16x16x32_bf16(feh, fxh[1][kc], A1, 0, 0, 0); \
            D0 = __builtin_amdgcn_mfma_f32_16x16x32_bf16(feh, fxm[0][kc], D0, 0, 0, 0); \
            D1 = __builtin_amdgcn_mfma_f32_16x16x32_bf16(feh, fxm[1][kc], D1, 0, 0, 0); \
            D0 = __builtin_amdgcn_mfma_f32_16x16x32_bf16(fem, fxh[0][kc], D0, 0, 0, 0); \
            D1 = __builtin_amdgcn_mfma_f32_16x16x32_bf16(fem, fxh[1][kc], D1, 0, 0, 0); \
        }                                                                    \
        __builtin_amdgcn_s_setprio(0);                                       \
        const int kbase = _m0 + lg * 4;                                      \
        _Pragma("unroll")                                                    \
        for (int r = 0; r < 4; ++r) {                                        \
            {   float v = fmaf(-2.0f, A0[r] + D0[r], nrm[r]);                \
                int kk = kbase + r;                                          \
                bool lt = v < m1_0;                                          \
                m2_0 = lt ? m1_0 : fminf(m2_0, v);                           \
                k1_0 = lt ? kk : k1_0;                                       \
                m1_0 = lt ? v : m1_0; }                                      \
            {   float v = fmaf(-2.0f, A1[r] + D1[r], nrm[r]);                \
                int kk = kbase + r;                                          \
                bool lt = v < m1_1;                                          \
                m2_1 = lt ? m1_1 : fminf(m2_1, v);                           \
                k1_1 = lt ? kk : k1_1;                                       \
                m1_1 = lt ? v : m1_1; }                                      \
        }                                                                    \
        if (DO_ISSUE) { VQ_STAGE((T) + 3); }                                 \
    } while (0)

    for (int t = 0; t < 60; ++t) VQ_ITER(t, 4, true);
    VQ_ITER(60, 4, true);    // issues tile 63
    VQ_ITER(61, 4, false);
    VQ_ITER(62, 2, false);
    VQ_ITER(63, 0, false);
#undef VQ_ITER
#undef VQ_STAGE

    // merge the 4 lane-groups (each saw a disjoint k-subset) per row
    #pragma unroll
    for (int off = 16; off <= 32; off <<= 1) {
        {   float om1 = __shfl_xor(m1_0, off, 64);
            float om2 = __shfl_xor(m2_0, off, 64);
            int   ok1 = __shfl_xor(k1_0, off, 64);
            float hi = fmaxf(m1_0, om1);
            m2_0 = fminf(fminf(m2_0, om2), hi);
            bool take = om1 < m1_0;
            k1_0 = take ? ok1 : k1_0;
            m1_0 = fminf(m1_0, om1); }
        {   float om1 = __shfl_xor(m1_1, off, 64);
            float om2 = __shfl_xor(m2_1, off, 64);
            int   ok1 = __shfl_xor(k1_1, off, 64);
            float hi = fmaxf(m1_1, om1);
            m2_1 = fminf(fminf(m2_1, om2), hi);
            bool take = om1 < m1_1;
            k1_1 = take ? ok1 : k1_1;
            m1_1 = fminf(m1_1, om1); }
    }

    if (lane < 16) {
        #pragma unroll
        for (int nt = 0; nt < 2; ++nt) {
            const int row = rtile + nt * 16 + lane;
            float m1 = nt ? m1_1 : m1_0;
            float m2 = nt ? m2_1 : m2_0;
            int   k1 = nt ? k1_1 : k1_0;
            if (m2 - m1 < W_DIST) {          // ambiguous under rounding: refine
                int slot = atomicAdd(fb_cnt, 1);
                fb_rows[slot] = row;
            } else {
                bestk[row] = k1;
                idx_out[row] = (float)k1;
            }
        }
    }
}

// ---- exact fallback: one wave per ambiguous row, bit-replicated formula ----
__global__ __launch_bounds__(256, 2) void vq_fallback(
        const float* __restrict__ x, const float* __restrict__ emb,
        const float* __restrict__ enorm,
        const int* __restrict__ fb_cnt, const int* __restrict__ fb_rows,
        int* __restrict__ bestk, float* __restrict__ idx_out) {
    const int lane = threadIdx.x & 63;
    const int wgid = blockIdx.x * 4 + (threadIdx.x >> 6);
    const int nw = gridDim.x * 4;
    const int n = *fb_cnt;
    for (int i = wgid; i < n; i += nw) {
        const int row = fb_rows[i];
        const float4* xr = reinterpret_cast<const float4*>(x + (size_t)row * DIM);
        float r8[8];
        {
            float4 a = xr[0], b = xr[1];
            r8[0] = __fmul_rn(a.x, a.x); r8[1] = __fmul_rn(a.y, a.y);
            r8[2] = __fmul_rn(a.z, a.z); r8[3] = __fmul_rn(a.w, a.w);
            r8[4] = __fmul_rn(b.x, b.x); r8[5] = __fmul_rn(b.y, b.y);
            r8[6] = __fmul_rn(b.z, b.z); r8[7] = __fmul_rn(b.w, b.w);
            for (int q = 1; q < 16; ++q) {
                float4 c = xr[2 * q], d = xr[2 * q + 1];
                r8[0] = __fadd_rn(r8[0], __fmul_rn(c.x, c.x));
                r8[1] = __fadd_rn(r8[1], __fmul_rn(c.y, c.y));
                r8[2] = __fadd_rn(r8[2], __fmul_rn(c.z, c.z));
                r8[3] = __fadd_rn(r8[3], __fmul_rn(c.w, c.w));
                r8[4] = __fadd_rn(r8[4], __fmul_rn(d.x, d.x));
                r8[5] = __fadd_rn(r8[5], __fmul_rn(d.y, d.y));
                r8[6] = __fadd_rn(r8[6], __fmul_rn(d.z, d.z));
                r8[7] = __fadd_rn(r8[7], __fmul_rn(d.w, d.w));
            }
        }
        float xnorm = __fadd_rn(
            __fadd_rn(__fadd_rn(r8[0], r8[1]), __fadd_rn(r8[2], r8[3])),
            __fadd_rn(__fadd_rn(r8[4], r8[5]), __fadd_rn(r8[6], r8[7])));

        float bv = 3.402823466e38f; int bk = 0;
        for (int j = 0; j < 16; ++j) {
            const int k = lane + j * 64;     // ascending k per lane
            const float4* er = reinterpret_cast<const float4*>(emb + (size_t)k * DIM);
            float d0 = 0.f, d1 = 0.f, d2 = 0.f, d3 = 0.f;
            #pragma unroll
            for (int q = 0; q < 32; ++q) {
                float4 ev = er[q]; float4 xv = xr[q];
                d0 = fmaf(xv.x, ev.x, d0);
                d1 = fmaf(xv.y, ev.y, d1);
                d2 = fmaf(xv.z, ev.z, d2);
                d3 = fmaf(xv.w, ev.w, d3);
            }
            float dot = __fadd_rn(__fadd_rn(d0, d1), __fadd_rn(d2, d3));
            float s = __fsub_rn(__fadd_rn(xnorm, enorm[k]), __fmul_rn(2.0f, dot));
            if (s < bv) { bv = s; bk = k; }
        }
        #pragma unroll
        for (int off = 1; off < 64; off <<= 1) {
            float ov = __shfl_xor(bv, off, 64);
            int   ok = __shfl_xor(bk, off, 64);
            bool take = (ov < bv) || (ov == bv && ok < bk);
            bv = take ? ov : bv;
            bk = take ? ok : bk;
        }
        if (lane == 0) { bestk[row] = bk; idx_out[row] = (float)bk; }
    }
}

// ---- gather quantized rows + per-block loss partials (no atomics) ---------
__global__ __launch_bounds__(256) void vq_gather(
        const float* __restrict__ x, const float* __restrict__ emb,
        const int* __restrict__ bestk, float* __restrict__ quant,
        double* __restrict__ partials) {
    const int t = blockIdx.x * 256 + threadIdx.x;   // 1048576 threads, 8 elems
    const int r = t >> 4;
    const int c = (t & 15) * 8;
    const int bk = bestk[r];
    const float4* ep = reinterpret_cast<const float4*>(emb + (size_t)bk * DIM + c);
    const float4* xp = reinterpret_cast<const float4*>(x + (size_t)r * DIM + c);
    float4 e0 = ep[0], e1 = ep[1];
    float4 x0 = xp[0], x1 = xp[1];
    float* q = quant + (size_t)r * DIM + c;   // base misaligned by 1 float
    q[0] = e0.x; q[1] = e0.y; q[2] = e0.z; q[3] = e0.w;
    q[4] = e1.x; q[5] = e1.y; q[6] = e1.z; q[7] = e1.w;
    float d0 = e0.x - x0.x, d1 = e0.y - x0.y, d2 = e0.z - x0.z, d3 = e0.w - x0.w;
    float d4 = e1.x - x1.x, d5 = e1.y - x1.y, d6 = e1.z - x1.z, d7 = e1.w - x1.w;
    float acc = fmaf(d0, d0, fmaf(d1, d1, fmaf(d2, d2, d3 * d3)))
              + fmaf(d4, d4, fmaf(d5, d5, fmaf(d6, d6, d7 * d7)));
    #pragma unroll
    for (int off = 32; off > 0; off >>= 1) acc += __shfl_down(acc, off, 64);

    __shared__ float sacc[4];
    if ((threadIdx.x & 63) == 0) sacc[threadIdx.x >> 6] = acc;
    __syncthreads();
    if (threadIdx.x == 0)
        partials[blockIdx.x] =
            (double)sacc[0] + (double)sacc[1] + (double)sacc[2] + (double)sacc[3];
}

// ---- final loss: sum 4096 block partials in one block ---------------------
__global__ __launch_bounds__(256) void vq_loss(
        const double* __restrict__ partials, float* __restrict__ out) {
    double s = 0.0;
    #pragma unroll
    for (int i = 0; i < 16; ++i) s += partials[threadIdx.x + i * 256];
    #pragma unroll
    for (int off = 32; off > 0; off >>= 1) s += __shfl_down(s, off, 64);
    __shared__ double sd[4];
    if ((threadIdx.x & 63) == 0) sd[threadIdx.x >> 6] = s;
    __syncthreads();
    if (threadIdx.x == 0)
        out[0] = (float)((sd[0] + sd[1] + sd[2] + sd[3]) * (1.25 / 8388608.0));
}

extern "C" void kernel_launch(void* const* d_in, const int* in_sizes, int n_in,
                              void* d_out, int out_size, void* d_ws, size_t ws_size,
                              hipStream_t stream) {
    const float* x   = (const float*)d_in[0];   // [32,2048,128] f32
    const float* emb = (const float*)d_in[1];   // [1024,128] f32

    float* out      = (float*)d_out;
    float* loss_out = out;
    float* quant    = out + 1;                        // [8388608]
    float* idx_out  = out + 1 + (size_t)NROWS * DIM;  // [65536] as float

    char* ws = (char*)d_ws;
    int*    fb_cnt   = (int*)(ws + 8);
    float*  enorm    = (float*)(ws + 1024);             // 4 KB
    int*    fb_rows  = (int*)(ws + 16384);              // 256 KB
    int*    bestk    = (int*)(ws + 278528);             // 256 KB
    unsigned short* eh = (unsigned short*)(ws + 557056); // 256 KB
    unsigned short* em = (unsigned short*)(ws + 819200); // 256 KB
    double* partials = (double*)(ws + 1081344);          // 32 KB

    hipMemsetAsync(ws, 0, 16, stream);
    vq_prep<<<4, 256, 0, stream>>>(emb, enorm, eh, em);
    vq_mfma<<<512, 256, 0, stream>>>(x, eh, em, enorm,
                                     bestk, idx_out, fb_cnt, fb_rows);
    vq_fallback<<<1024, 256, 0, stream>>>(x, emb, enorm, fb_cnt, fb_rows,
                                          bestk, idx_out);
    vq_gather<<<4096, 256, 0, stream>>>(x, emb, bestk, quant, partials);
    vq_loss<<<1, 256, 0, stream>>>(partials, loss_out);
}

// Round 8
// 113.244 us; speedup vs baseline: 5.6829x; 1.3669x over previous
//
#include <hip/hip_runtime.h>

#define NROWS 65536
#define KC    1024
#define DIM   128
#define W_DIST 5e-5f

typedef short  bf16x8 __attribute__((ext_vector_type(8)));
typedef float  f32x4  __attribute__((ext_vector_type(4)));

__device__ __forceinline__ unsigned short f2bf_rne(float f) {
    unsigned int u = __float_as_uint(f);
    u += 0x7FFFu + ((u >> 16) & 1u);
    return (unsigned short)(u >> 16);
}
__device__ __forceinline__ float bf2f(unsigned short h) {
    return __uint_as_float(((unsigned int)h) << 16);
}

// async global->LDS DMA, 16 B per lane; LDS dest = wave-uniform base + lane*16
__device__ __forceinline__ void gll16(const unsigned short* g, short* l) {
    __builtin_amdgcn_global_load_lds(
        (const __attribute__((address_space(1))) unsigned int*)g,
        (__attribute__((address_space(3))) unsigned int*)l,
        16, 0, 0);
}

template <int N>
__device__ __forceinline__ void vmwait() {
    if constexpr (N == 4)      asm volatile("s_waitcnt vmcnt(4)" ::: "memory");
    else if constexpr (N == 2) asm volatile("s_waitcnt vmcnt(2)" ::: "memory");
    else                       asm volatile("s_waitcnt vmcnt(0)" ::: "memory");
}

// numpy pairwise sum-of-squares for n=128 (8 stride-8 accumulators, tree combine)
__device__ __forceinline__ float np_sumsq_128(const float* v) {
    float r[8];
    #pragma unroll
    for (int j = 0; j < 8; ++j) r[j] = __fmul_rn(v[j], v[j]);
    #pragma unroll
    for (int i = 1; i < 16; ++i)
        #pragma unroll
        for (int j = 0; j < 8; ++j)
            r[j] = __fadd_rn(r[j], __fmul_rn(v[i * 8 + j], v[i * 8 + j]));
    return __fadd_rn(__fadd_rn(__fadd_rn(r[0], r[1]), __fadd_rn(r[2], r[3])),
                     __fadd_rn(__fadd_rn(r[4], r[5]), __fadd_rn(r[6], r[7])));
}

// ---- codebook prep: exact norms + bf16 hi/mid split (fused) ---------------
__global__ __launch_bounds__(256) void vq_prep(const float* __restrict__ emb,
        float* __restrict__ enorm,
        unsigned short* __restrict__ eh, unsigned short* __restrict__ em) {
    const int k = blockIdx.x * 256 + threadIdx.x;
    if (k >= KC) return;
    float v[DIM];
    const float4* e = reinterpret_cast<const float4*>(emb + (size_t)k * DIM);
    #pragma unroll
    for (int i = 0; i < 32; ++i) {
        float4 t = e[i];
        v[i * 4 + 0] = t.x; v[i * 4 + 1] = t.y;
        v[i * 4 + 2] = t.z; v[i * 4 + 3] = t.w;
    }
    enorm[k] = np_sumsq_128(v);
    unsigned short* ph = eh + (size_t)k * DIM;
    unsigned short* pm = em + (size_t)k * DIM;
    #pragma unroll
    for (int i = 0; i < 16; ++i) {
        unsigned int h[8], m[8];
        #pragma unroll
        for (int j = 0; j < 8; ++j) {
            float f = v[i * 8 + j];
            unsigned short hh = f2bf_rne(f);
            h[j] = hh;
            m[j] = f2bf_rne(f - bf2f(hh));
        }
        uint4 vh = {h[0] | (h[1] << 16), h[2] | (h[3] << 16),
                    h[4] | (h[5] << 16), h[6] | (h[7] << 16)};
        uint4 vm = {m[0] | (m[1] << 16), m[2] | (m[3] << 16),
                    m[4] | (m[5] << 16), m[6] | (m[7] << 16)};
        *reinterpret_cast<uint4*>(ph + i * 8) = vh;
        *reinterpret_cast<uint4*>(pm + i * 8) = vm;
    }
}

// ---- main MFMA distance + top-2 kernel (unchanged from round 7) -----------
__global__ __launch_bounds__(256, 2) void vq_mfma(
        const float* __restrict__ x,
        const unsigned short* __restrict__ eh, const unsigned short* __restrict__ em,
        const float* __restrict__ enorm,
        int* __restrict__ bestk, float* __restrict__ idx_out,
        int* __restrict__ fb_cnt, int* __restrict__ fb_rows) {
    const int tid  = threadIdx.x;
    const int lane = tid & 63;
    const int wid  = tid >> 6;
    const int rtile = blockIdx.x * 128 + wid * 32;
    const int lr = lane & 15;
    const int lg = lane >> 4;

    __shared__ short ldsE[4][2][2048];   // [buf][hi/mid][16x128 bf16] = 32 KB
    __shared__ float s_enorm[KC];        // 4 KB

    const int s_row = tid & 15;
    const int s_col = ((tid >> 6) * 32) + (((tid >> 4) & 3) * 8);
    const unsigned short* geh = eh + (size_t)s_row * DIM + s_col;
    const unsigned short* gem = em + (size_t)s_row * DIM + s_col;

#define VQ_STAGE(T)                                                         \
    do {                                                                    \
        const int _b = (T) & 3;                                             \
        gll16(geh + (size_t)(T) * 2048, (short*)&ldsE[_b][0][0] + wid * 512); \
        gll16(gem + (size_t)(T) * 2048, (short*)&ldsE[_b][1][0] + wid * 512); \
    } while (0)

    VQ_STAGE(0); VQ_STAGE(1); VQ_STAGE(2);

    bf16x8 fxh[2][4], fxm[2][4];
    #pragma unroll
    for (int nt = 0; nt < 2; ++nt) {
        const float* px = x + (size_t)(rtile + nt * 16 + lr) * DIM + lg * 8;
        #pragma unroll
        for (int kc = 0; kc < 4; ++kc) {
            float4 a = *reinterpret_cast<const float4*>(px + kc * 32);
            float4 b = *reinterpret_cast<const float4*>(px + kc * 32 + 4);
            float f[8] = {a.x, a.y, a.z, a.w, b.x, b.y, b.z, b.w};
            bf16x8 vh, vm;
            #pragma unroll
            for (int j = 0; j < 8; ++j) {
                unsigned short hh = f2bf_rne(f[j]);
                vh[j] = (short)hh;
                vm[j] = (short)f2bf_rne(f[j] - bf2f(hh));
            }
            fxh[nt][kc] = vh;
            fxm[nt][kc] = vm;
        }
    }
    #pragma unroll
    for (int nt = 0; nt < 2; ++nt)
        #pragma unroll
        for (int kc = 0; kc < 4; ++kc)
            asm volatile("" : "+v"(fxh[nt][kc]), "+v"(fxm[nt][kc]));

    *reinterpret_cast<float4*>(&s_enorm[tid * 4]) =
        *reinterpret_cast<const float4*>(&enorm[tid * 4]);
    __syncthreads();

    float m1_0 = 1e30f, m2_0 = 1e30f; int k1_0 = 0;
    float m1_1 = 1e30f, m2_1 = 1e30f; int k1_1 = 0;

#define VQ_ITER(T, VMN, DO_ISSUE)                                            \
    do {                                                                     \
        vmwait<VMN>();                                                       \
        __builtin_amdgcn_s_barrier();                                        \
        asm volatile("" ::: "memory");                                       \
        const int _buf = (T) & 3;                                            \
        const int _m0 = (T) * 16;                                            \
        const f32x4 nrm = *reinterpret_cast<const f32x4*>(&s_enorm[_m0 + lg * 4]); \
        f32x4 A0 = {0.f,0.f,0.f,0.f}, A1 = {0.f,0.f,0.f,0.f};                \
        f32x4 D0 = {0.f,0.f,0.f,0.f}, D1 = {0.f,0.f,0.f,0.f};                \
        __builtin_amdgcn_s_setprio(1);                                       \
        _Pragma("unroll")                                                    \
        for (int kc = 0; kc < 4; ++kc) {                                     \
            const int off = ((kc * 4 + lg) * 16 + lr) * 8;                   \
            bf16x8 feh = *reinterpret_cast<const bf16x8*>(&ldsE[_buf][0][off]); \
            bf16x8 fem = *reinterpret_cast<const bf16x8*>(&ldsE[_buf][1][off]); \
            A0 = __builtin_amdgcn_mfma_f32_16x16x32_bf16(feh, fxh[0][kc], A0, 0, 0, 0); \
            A1 = __builtin_amdgcn_mfma_f32_16x16x32_bf16(feh, fxh[1][kc], A1, 0, 0, 0); \
            D0 = __builtin_amdgcn_mfma_f32_16x16x32_bf16(feh, fxm[0][kc], D0, 0, 0, 0); \
            D1 = __builtin_amdgcn_mfma_f32_16x16x32_bf16(feh, fxm[1][kc], D1, 0, 0, 0); \
            D0 = __builtin_amdgcn_mfma_f32_16x16x32_bf16(fem, fxh[0][kc], D0, 0, 0, 0); \
            D1 = __builtin_amdgcn_mfma_f32_16x16x32_bf16(fem, fxh[1][kc], D1, 0, 0, 0); \
        }                                                                    \
        __builtin_amdgcn_s_setprio(0);                                       \
        const int kbase = _m0 + lg * 4;                                      \
        _Pragma("unroll")                                                    \
        for (int r = 0; r < 4; ++r) {                                        \
            {   float v = fmaf(-2.0f, A0[r] + D0[r], nrm[r]);                \
                int kk = kbase + r;                                          \
                bool lt = v < m1_0;                                          \
                m2_0 = lt ? m1_0 : fminf(m2_0, v);                           \
                k1_0 = lt ? kk : k1_0;                                       \
                m1_0 = lt ? v : m1_0; }                                      \
            {   float v = fmaf(-2.0f, A1[r] + D1[r], nrm[r]);                \
                int kk = kbase + r;                                          \
                bool lt = v < m1_1;                                          \
                m2_1 = lt ? m1_1 : fminf(m2_1, v);                           \
                k1_1 = lt ? kk : k1_1;                                       \
                m1_1 = lt ? v : m1_1; }                                      \
        }                                                                    \
        if (DO_ISSUE) { VQ_STAGE((T) + 3); }                                 \
    } while (0)

    for (int t = 0; t < 60; ++t) VQ_ITER(t, 4, true);
    VQ_ITER(60, 4, true);
    VQ_ITER(61, 4, false);
    VQ_ITER(62, 2, false);
    VQ_ITER(63, 0, false);
#undef VQ_ITER
#undef VQ_STAGE

    #pragma unroll
    for (int off = 16; off <= 32; off <<= 1) {
        {   float om1 = __shfl_xor(m1_0, off, 64);
            float om2 = __shfl_xor(m2_0, off, 64);
            int   ok1 = __shfl_xor(k1_0, off, 64);
            float hi = fmaxf(m1_0, om1);
            m2_0 = fminf(fminf(m2_0, om2), hi);
            bool take = om1 < m1_0;
            k1_0 = take ? ok1 : k1_0;
            m1_0 = fminf(m1_0, om1); }
        {   float om1 = __shfl_xor(m1_1, off, 64);
            float om2 = __shfl_xor(m2_1, off, 64);
            int   ok1 = __shfl_xor(k1_1, off, 64);
            float hi = fmaxf(m1_1, om1);
            m2_1 = fminf(fminf(m2_1, om2), hi);
            bool take = om1 < m1_1;
            k1_1 = take ? ok1 : k1_1;
            m1_1 = fminf(m1_1, om1); }
    }

    if (lane < 16) {
        #pragma unroll
        for (int nt = 0; nt < 2; ++nt) {
            const int row = rtile + nt * 16 + lane;
            float m1 = nt ? m1_1 : m1_0;
            float m2 = nt ? m2_1 : m2_0;
            int   k1 = nt ? k1_1 : k1_0;
            if (m2 - m1 < W_DIST) {
                int slot = atomicAdd(fb_cnt, 1);
                fb_rows[slot] = row;
            } else {
                bestk[row] = k1;
                idx_out[row] = (float)k1;
            }
        }
    }
}

// ---- exact fallback: block-cooperative, 8 rows per codebook pass ----------
// 512 threads; thread t owns k = t and k = 512+t. Per-(row,k) arithmetic is
// bit-identical to the validated wave-per-row version: 4 fmaf chains in the
// same q order, same __fadd_rn/__fsub_rn/__fmul_rn combine, numpy-pairwise
// xnorm. First-occurrence argmin via lexicographic (value,k) reduction.
__global__ __launch_bounds__(512) void vq_fallback(
        const float* __restrict__ x, const float* __restrict__ emb,
        const float* __restrict__ enorm,
        const int* __restrict__ fb_cnt, const int* __restrict__ fb_rows,
        int* __restrict__ bestk, float* __restrict__ idx_out) {
    const int tid  = threadIdx.x;
    const int lane = tid & 63;
    const int wid  = tid >> 6;          // 8 waves
    const int nb = *fb_cnt;

    __shared__ float sx[8][DIM];        // 4 KB staged x rows
    __shared__ float s_xn[8];
    __shared__ float swv[8][8];         // [wave][row] candidates
    __shared__ int   swk[8][8];

    const float en0 = enorm[tid];       // k0 = tid
    const float en1 = enorm[tid + 512]; // k1 = tid + 512
    const float4* e0p = reinterpret_cast<const float4*>(emb + (size_t)tid * DIM);
    const float4* e1p = reinterpret_cast<const float4*>(emb + (size_t)(tid + 512) * DIM);

    for (int base = blockIdx.x * 8; base < nb; base += gridDim.x * 8) {
        const int R = min(8, nb - base);
        // stage 8 x rows: thread t -> row t>>6, float2 at col (t&63)*2
        {
            const int r = tid >> 6;
            const int c2 = (tid & 63) * 2;
            const int slot = fb_rows[min(base + r, nb - 1)];
            float2 v = *reinterpret_cast<const float2*>(x + (size_t)slot * DIM + c2);
            sx[r][c2] = v.x; sx[r][c2 + 1] = v.y;
        }
        __syncthreads();
        if (tid < 8) s_xn[tid] = np_sumsq_128(&sx[tid][0]);
        __syncthreads();

        // accumulate dots: a0/a1[row][chain]
        float a0[8][4], a1[8][4];
        #pragma unroll
        for (int r = 0; r < 8; ++r)
            #pragma unroll
            for (int c = 0; c < 4; ++c) { a0[r][c] = 0.f; a1[r][c] = 0.f; }

        for (int q = 0; q < 32; ++q) {
            float4 ev0 = e0p[q];
            float4 ev1 = e1p[q];
            #pragma unroll
            for (int r = 0; r < 8; ++r) {
                float4 xv = *reinterpret_cast<const float4*>(&sx[r][q * 4]);
                a0[r][0] = fmaf(xv.x, ev0.x, a0[r][0]);
                a0[r][1] = fmaf(xv.y, ev0.y, a0[r][1]);
                a0[r][2] = fmaf(xv.z, ev0.z, a0[r][2]);
                a0[r][3] = fmaf(xv.w, ev0.w, a0[r][3]);
                a1[r][0] = fmaf(xv.x, ev1.x, a1[r][0]);
                a1[r][1] = fmaf(xv.y, ev1.y, a1[r][1]);
                a1[r][2] = fmaf(xv.z, ev1.z, a1[r][2]);
                a1[r][3] = fmaf(xv.w, ev1.w, a1[r][3]);
            }
        }

        // finalize + per-wave lexicographic (value, k) reduce, per row
        float cv[8]; int ck[8];
        #pragma unroll
        for (int r = 0; r < 8; ++r) {
            float xn = s_xn[r];
            float d0 = __fadd_rn(__fadd_rn(a0[r][0], a0[r][1]),
                                 __fadd_rn(a0[r][2], a0[r][3]));
            float s0 = __fsub_rn(__fadd_rn(xn, en0), __fmul_rn(2.0f, d0));
            float d1 = __fadd_rn(__fadd_rn(a1[r][0], a1[r][1]),
                                 __fadd_rn(a1[r][2], a1[r][3]));
            float s1 = __fsub_rn(__fadd_rn(xn, en1), __fmul_rn(2.0f, d1));
            bool t1 = (s1 < s0);          // k1 > k0, so strict < only
            cv[r] = t1 ? s1 : s0;
            ck[r] = t1 ? tid + 512 : tid;
        }
        #pragma unroll
        for (int off = 1; off < 64; off <<= 1) {
            #pragma unroll
            for (int r = 0; r < 8; ++r) {
                float ov = __shfl_xor(cv[r], off, 64);
                int   ok = __shfl_xor(ck[r], off, 64);
                bool take = (ov < cv[r]) || (ov == cv[r] && ok < ck[r]);
                cv[r] = take ? ov : cv[r];
                ck[r] = take ? ok : ck[r];
            }
        }
        if (lane == 0) {
            #pragma unroll
            for (int r = 0; r < 8; ++r) { swv[wid][r] = cv[r]; swk[wid][r] = ck[r]; }
        }
        __syncthreads();
        if (tid < R) {
            float bv = swv[0][tid]; int bk = swk[0][tid];
            #pragma unroll
            for (int w = 1; w < 8; ++w) {
                float v = swv[w][tid]; int k = swk[w][tid];
                bool take = (v < bv) || (v == bv && k < bk);
                bv = take ? v : bv;
                bk = take ? k : bk;
            }
            const int row = fb_rows[base + tid];
            bestk[row] = bk;
            idx_out[row] = (float)bk;
        }
        __syncthreads();   // protect sx before next iteration's staging
    }
}

// ---- gather quantized rows + per-block loss partials (no atomics) ---------
__global__ __launch_bounds__(256) void vq_gather(
        const float* __restrict__ x, const float* __restrict__ emb,
        const int* __restrict__ bestk, float* __restrict__ quant,
        double* __restrict__ partials) {
    const int t = blockIdx.x * 256 + threadIdx.x;   // 1048576 threads, 8 elems
    const int r = t >> 4;
    const int c = (t & 15) * 8;
    const int bk = bestk[r];
    const float4* ep = reinterpret_cast<const float4*>(emb + (size_t)bk * DIM + c);
    const float4* xp = reinterpret_cast<const float4*>(x + (size_t)r * DIM + c);
    float4 e0 = ep[0], e1 = ep[1];
    float4 x0 = xp[0], x1 = xp[1];
    float* q = quant + (size_t)r * DIM + c;   // base misaligned by 1 float
    q[0] = e0.x; q[1] = e0.y; q[2] = e0.z; q[3] = e0.w;
    q[4] = e1.x; q[5] = e1.y; q[6] = e1.z; q[7] = e1.w;
    float d0 = e0.x - x0.x, d1 = e0.y - x0.y, d2 = e0.z - x0.z, d3 = e0.w - x0.w;
    float d4 = e1.x - x1.x, d5 = e1.y - x1.y, d6 = e1.z - x1.z, d7 = e1.w - x1.w;
    float acc = fmaf(d0, d0, fmaf(d1, d1, fmaf(d2, d2, d3 * d3)))
              + fmaf(d4, d4, fmaf(d5, d5, fmaf(d6, d6, d7 * d7)));
    #pragma unroll
    for (int off = 32; off > 0; off >>= 1) acc += __shfl_down(acc, off, 64);

    __shared__ float sacc[4];
    if ((threadIdx.x & 63) == 0) sacc[threadIdx.x >> 6] = acc;
    __syncthreads();
    if (threadIdx.x == 0)
        partials[blockIdx.x] =
            (double)sacc[0] + (double)sacc[1] + (double)sacc[2] + (double)sacc[3];
}

// ---- final loss: sum 4096 block partials in one block ---------------------
__global__ __launch_bounds__(256) void vq_loss(
        const double* __restrict__ partials, float* __restrict__ out) {
    double s = 0.0;
    #pragma unroll
    for (int i = 0; i < 16; ++i) s += partials[threadIdx.x + i * 256];
    #pragma unroll
    for (int off = 32; off > 0; off >>= 1) s += __shfl_down(s, off, 64);
    __shared__ double sd[4];
    if ((threadIdx.x & 63) == 0) sd[threadIdx.x >> 6] = s;
    __syncthreads();
    if (threadIdx.x == 0)
        out[0] = (float)((sd[0] + sd[1] + sd[2] + sd[3]) * (1.25 / 8388608.0));
}

extern "C" void kernel_launch(void* const* d_in, const int* in_sizes, int n_in,
                              void* d_out, int out_size, void* d_ws, size_t ws_size,
                              hipStream_t stream) {
    const float* x   = (const float*)d_in[0];   // [32,2048,128] f32
    const float* emb = (const float*)d_in[1];   // [1024,128] f32

    float* out      = (float*)d_out;
    float* loss_out = out;
    float* quant    = out + 1;                        // [8388608]
    float* idx_out  = out + 1 + (size_t)NROWS * DIM;  // [65536] as float

    char* ws = (char*)d_ws;
    int*    fb_cnt   = (int*)(ws + 8);
    float*  enorm    = (float*)(ws + 1024);             // 4 KB
    int*    fb_rows  = (int*)(ws + 16384);              // 256 KB
    int*    bestk    = (int*)(ws + 278528);             // 256 KB
    unsigned short* eh = (unsigned short*)(ws + 557056); // 256 KB
    unsigned short* em = (unsigned short*)(ws + 819200); // 256 KB
    double* partials = (double*)(ws + 1081344);          // 32 KB

    hipMemsetAsync(ws, 0, 16, stream);
    vq_prep<<<4, 256, 0, stream>>>(emb, enorm, eh, em);
    vq_mfma<<<512, 256, 0, stream>>>(x, eh, em, enorm,
                                     bestk, idx_out, fb_cnt, fb_rows);
    vq_fallback<<<1024, 512, 0, stream>>>(x, emb, enorm, fb_cnt, fb_rows,
                                          bestk, idx_out);
    vq_gather<<<4096, 256, 0, stream>>>(x, emb, bestk, quant, partials);
    vq_loss<<<1, 256, 0, stream>>>(partials, loss_out);
}

// Round 9
// 110.416 us; speedup vs baseline: 5.8285x; 1.0256x over previous
//
#include <hip/hip_runtime.h>

#define NROWS 65536
#define KC    1024
#define DIM   128
#define W_DIST 5e-5f

typedef short  bf16x8 __attribute__((ext_vector_type(8)));
typedef float  f32x4  __attribute__((ext_vector_type(4)));
typedef float  f32x16 __attribute__((ext_vector_type(16)));

#define ZERO16 ((f32x16){0.f,0.f,0.f,0.f,0.f,0.f,0.f,0.f,0.f,0.f,0.f,0.f,0.f,0.f,0.f,0.f})

__device__ __forceinline__ unsigned short f2bf_rne(float f) {
    unsigned int u = __float_as_uint(f);
    u += 0x7FFFu + ((u >> 16) & 1u);
    return (unsigned short)(u >> 16);
}
__device__ __forceinline__ float bf2f(unsigned short h) {
    return __uint_as_float(((unsigned int)h) << 16);
}

// async global->LDS DMA, 16 B per lane; LDS dest = wave-uniform base + lane*16
__device__ __forceinline__ void gll16(const unsigned short* g, short* l) {
    __builtin_amdgcn_global_load_lds(
        (const __attribute__((address_space(1))) unsigned int*)g,
        (__attribute__((address_space(3))) unsigned int*)l,
        16, 0, 0);
}

template <int N>
__device__ __forceinline__ void vmwait() {
    if constexpr (N == 8)      asm volatile("s_waitcnt vmcnt(8)" ::: "memory");
    else if constexpr (N == 4) asm volatile("s_waitcnt vmcnt(4)" ::: "memory");
    else if constexpr (N == 2) asm volatile("s_waitcnt vmcnt(2)" ::: "memory");
    else                       asm volatile("s_waitcnt vmcnt(0)" ::: "memory");
}

// numpy pairwise sum-of-squares for n=128 (8 stride-8 accumulators, tree combine)
__device__ __forceinline__ float np_sumsq_128(const float* v) {
    float r[8];
    #pragma unroll
    for (int j = 0; j < 8; ++j) r[j] = __fmul_rn(v[j], v[j]);
    #pragma unroll
    for (int i = 1; i < 16; ++i)
        #pragma unroll
        for (int j = 0; j < 8; ++j)
            r[j] = __fadd_rn(r[j], __fmul_rn(v[i * 8 + j], v[i * 8 + j]));
    return __fadd_rn(__fadd_rn(__fadd_rn(r[0], r[1]), __fadd_rn(r[2], r[3])),
                     __fadd_rn(__fadd_rn(r[4], r[5]), __fadd_rn(r[6], r[7])));
}

// ---- codebook prep: exact norms + bf16 hi/mid split (fused) ---------------
__global__ __launch_bounds__(256) void vq_prep(const float* __restrict__ emb,
        float* __restrict__ enorm,
        unsigned short* __restrict__ eh, unsigned short* __restrict__ em) {
    const int k = blockIdx.x * 256 + threadIdx.x;
    if (k >= KC) return;
    float v[DIM];
    const float4* e = reinterpret_cast<const float4*>(emb + (size_t)k * DIM);
    #pragma unroll
    for (int i = 0; i < 32; ++i) {
        float4 t = e[i];
        v[i * 4 + 0] = t.x; v[i * 4 + 1] = t.y;
        v[i * 4 + 2] = t.z; v[i * 4 + 3] = t.w;
    }
    enorm[k] = np_sumsq_128(v);
    unsigned short* ph = eh + (size_t)k * DIM;
    unsigned short* pm = em + (size_t)k * DIM;
    #pragma unroll
    for (int i = 0; i < 16; ++i) {
        unsigned int h[8], m[8];
        #pragma unroll
        for (int j = 0; j < 8; ++j) {
            float f = v[i * 8 + j];
            unsigned short hh = f2bf_rne(f);
            h[j] = hh;
            m[j] = f2bf_rne(f - bf2f(hh));
        }
        uint4 vh = {h[0] | (h[1] << 16), h[2] | (h[3] << 16),
                    h[4] | (h[5] << 16), h[6] | (h[7] << 16)};
        uint4 vm = {m[0] | (m[1] << 16), m[2] | (m[3] << 16),
                    m[4] | (m[5] << 16), m[6] | (m[7] << 16)};
        *reinterpret_cast<uint4*>(ph + i * 8) = vh;
        *reinterpret_cast<uint4*>(pm + i * 8) = vm;
    }
}

// ---- main MFMA distance + top-2 kernel ------------------------------------
// 32x32x16 MFMA. Wave owns 32 x-rows; 32 k-tiles of 32 codebook rows each.
// 3-buffer LDS rotation (stage T+2 -> buf (T+2)%3 == retired buf (T-1)%3),
// counted vmcnt(4), double-buffered accumulators: epilogue of tile T runs
// after tile T+1's MFMAs are issued (VALU hides under the matrix pipe).
__global__ __launch_bounds__(256, 2) void vq_mfma(
        const float* __restrict__ x,
        const unsigned short* __restrict__ eh, const unsigned short* __restrict__ em,
        const float* __restrict__ enorm,
        int* __restrict__ bestk, float* __restrict__ idx_out,
        int* __restrict__ fb_cnt, int* __restrict__ fb_rows) {
    const int tid  = threadIdx.x;
    const int lane = tid & 63;
    const int wid  = tid >> 6;
    const int lr31 = lane & 31;
    const int hi   = lane >> 5;
    const int rtile = blockIdx.x * 128 + wid * 32;

    __shared__ short ldsE[3][2][4096];   // 3 bufs x (hi,mid) x 8 KB = 48 KB
    __shared__ float s_enorm[KC];        // 4 KB

    // staging decode: unit u (16 B) = [s2 = u>>5][row = u&31]; wave w owns
    // units w*128..+127 per half-tile via 2 gll16 calls
    const int u0 = wid * 128 + lane;
    const int u1 = wid * 128 + 64 + lane;
    const int src0 = (u0 & 31) * DIM + (u0 >> 5) * 8;
    const int src1 = (u1 & 31) * DIM + (u1 >> 5) * 8;
    const int dst0 = wid * 128 * 8;          // in shorts
    const int dst1 = (wid * 128 + 64) * 8;

#define VQ_STAGE(T, B)                                                      \
    do {                                                                    \
        const unsigned short* _gh = eh + (size_t)(T) * 4096;                \
        const unsigned short* _gm = em + (size_t)(T) * 4096;                \
        gll16(_gh + src0, &ldsE[B][0][dst0]);                               \
        gll16(_gh + src1, &ldsE[B][0][dst1]);                               \
        gll16(_gm + src0, &ldsE[B][1][dst0]);                               \
        gll16(_gm + src1, &ldsE[B][1][dst1]);                               \
    } while (0)

    // X fragments: lane owns row rtile+lr31, k = s*16 + hi*8 .. +8 (s=0..7);
    // lane^32 holds the other k-half of the same row.
    bf16x8 fxh[8], fxm[8];
    {
        const float* px = x + (size_t)(rtile + lr31) * DIM + hi * 8;
        #pragma unroll
        for (int s = 0; s < 8; ++s) {
            float4 a = *reinterpret_cast<const float4*>(px + s * 16);
            float4 b = *reinterpret_cast<const float4*>(px + s * 16 + 4);
            float f[8] = {a.x, a.y, a.z, a.w, b.x, b.y, b.z, b.w};
            bf16x8 vh, vm;
            #pragma unroll
            for (int j = 0; j < 8; ++j) {
                unsigned short hh = f2bf_rne(f[j]);
                vh[j] = (short)hh;
                vm[j] = (short)f2bf_rne(f[j] - bf2f(hh));
            }
            fxh[s] = vh; fxm[s] = vm;
        }
    }
    #pragma unroll
    for (int s = 0; s < 8; ++s)
        asm volatile("" : "+v"(fxh[s]), "+v"(fxm[s]));

    // enorm -> LDS (4 KB)
    *reinterpret_cast<float4*>(&s_enorm[tid * 4]) =
        *reinterpret_cast<const float4*>(&enorm[tid * 4]);

    VQ_STAGE(0, 0);
    VQ_STAGE(1, 1);

    // commit own ds_writes, sync; do NOT drain the staging DMA (vmcnt stays hot)
    asm volatile("s_waitcnt lgkmcnt(0)" ::: "memory");
    __builtin_amdgcn_s_barrier();

    float m1 = 1e30f, m2 = 1e30f; int k1 = 0;
    f32x16 aE, dE, aO, dO;

#define VQ_EPI(T, PA, PD)                                                   \
    do {                                                                    \
        const int _kb = (T) * 32 + (hi << 2);                               \
        _Pragma("unroll")                                                   \
        for (int g = 0; g < 4; ++g) {                                       \
            const f32x4 _nr = *reinterpret_cast<const f32x4*>(&s_enorm[_kb + g * 8]); \
            _Pragma("unroll")                                               \
            for (int j = 0; j < 4; ++j) {                                   \
                const int _r = g * 4 + j;                                   \
                float _v = fmaf(-2.0f, PA[_r] + PD[_r], _nr[j]);            \
                int _kk = _kb + g * 8 + j;                                  \
                bool _lt = _v < m1;                                         \
                m2 = fminf(m2, fmaxf(m1, _v));                              \
                k1 = _lt ? _kk : k1;                                        \
                m1 = fminf(m1, _v);                                         \
            }                                                               \
        }                                                                   \
    } while (0)

#define VQ_ITER(T, B, SB, CA, CD, PA, PD, VMN, DOSTAGE, DOEPI)              \
    do {                                                                    \
        vmwait<VMN>();                                                      \
        __builtin_amdgcn_s_barrier();                                       \
        asm volatile("" ::: "memory");                                      \
        CA = ZERO16; CD = ZERO16;                                           \
        __builtin_amdgcn_s_setprio(1);                                      \
        _Pragma("unroll")                                                   \
        for (int s = 0; s < 8; ++s) {                                       \
            const int _u = ((s * 2 + hi) * 32 + lr31) * 8;                  \
            bf16x8 feh = *reinterpret_cast<const bf16x8*>(&ldsE[B][0][_u]); \
            bf16x8 fem = *reinterpret_cast<const bf16x8*>(&ldsE[B][1][_u]); \
            CA = __builtin_amdgcn_mfma_f32_32x32x16_bf16(feh, fxh[s], CA, 0, 0, 0); \
            CD = __builtin_amdgcn_mfma_f32_32x32x16_bf16(feh, fxm[s], CD, 0, 0, 0); \
            CD = __builtin_amdgcn_mfma_f32_32x32x16_bf16(fem, fxh[s], CD, 0, 0, 0); \
        }                                                                   \
        __builtin_amdgcn_s_setprio(0);                                      \
        if (DOSTAGE) { VQ_STAGE((T) + 2, SB); }                             \
        if (DOEPI)   { VQ_EPI((T) - 1, PA, PD); }                           \
    } while (0)

    VQ_ITER(0, 0, 2, aE, dE, aO, dO, 4, 1, 0);
    VQ_ITER(1, 1, 0, aO, dO, aE, dE, 4, 1, 1);
    VQ_ITER(2, 2, 1, aE, dE, aO, dO, 4, 1, 1);
    VQ_ITER(3, 0, 2, aO, dO, aE, dE, 4, 1, 1);
    VQ_ITER(4, 1, 0, aE, dE, aO, dO, 4, 1, 1);
    VQ_ITER(5, 2, 1, aO, dO, aE, dE, 4, 1, 1);
    for (int tb = 6; tb < 30; tb += 6) {
        VQ_ITER(tb + 0, 0, 2, aE, dE, aO, dO, 4, 1, 1);
        VQ_ITER(tb + 1, 1, 0, aO, dO, aE, dE, 4, 1, 1);
        VQ_ITER(tb + 2, 2, 1, aE, dE, aO, dO, 4, 1, 1);
        VQ_ITER(tb + 3, 0, 2, aO, dO, aE, dE, 4, 1, 1);
        VQ_ITER(tb + 4, 1, 0, aE, dE, aO, dO, 4, 1, 1);
        VQ_ITER(tb + 5, 2, 1, aO, dO, aE, dE, 4, 1, 1);
    }
    VQ_ITER(30, 0, 2, aE, dE, aO, dO, 4, 0, 1);
    VQ_ITER(31, 1, 0, aO, dO, aE, dE, 0, 0, 1);
    VQ_EPI(31, aO, dO);
#undef VQ_ITER
#undef VQ_EPI
#undef VQ_STAGE

    // merge the two k-subsets per x-row (lane L and L+32 share row lane&31)
    {
        float om1 = __shfl_xor(m1, 32, 64);
        float om2 = __shfl_xor(m2, 32, 64);
        int   ok1 = __shfl_xor(k1, 32, 64);
        float mx = fmaxf(m1, om1);
        m2 = fminf(fminf(m2, om2), mx);
        bool take = (om1 < m1) || (om1 == m1 && ok1 < k1);
        k1 = take ? ok1 : k1;
        m1 = fminf(m1, om1);
    }
    if (lane < 32) {
        const int row = rtile + lane;
        if (m2 - m1 < W_DIST) {          // ambiguous under rounding: refine
            int slot = atomicAdd(fb_cnt, 1);
            fb_rows[slot] = row;
        } else {
            bestk[row] = k1;
            idx_out[row] = (float)k1;
        }
    }
}

// ---- exact fallback: block-cooperative, 8 rows per codebook pass ----------
__global__ __launch_bounds__(512) void vq_fallback(
        const float* __restrict__ x, const float* __restrict__ emb,
        const float* __restrict__ enorm,
        const int* __restrict__ fb_cnt, const int* __restrict__ fb_rows,
        int* __restrict__ bestk, float* __restrict__ idx_out) {
    const int tid  = threadIdx.x;
    const int lane = tid & 63;
    const int wid  = tid >> 6;          // 8 waves
    const int nb = *fb_cnt;

    __shared__ float sx[8][DIM];        // 4 KB staged x rows
    __shared__ float s_xn[8];
    __shared__ float swv[8][8];         // [wave][row] candidates
    __shared__ int   swk[8][8];

    const float en0 = enorm[tid];       // k0 = tid
    const float en1 = enorm[tid + 512]; // k1 = tid + 512
    const float4* e0p = reinterpret_cast<const float4*>(emb + (size_t)tid * DIM);
    const float4* e1p = reinterpret_cast<const float4*>(emb + (size_t)(tid + 512) * DIM);

    for (int base = blockIdx.x * 8; base < nb; base += gridDim.x * 8) {
        const int R = min(8, nb - base);
        {
            const int r = tid >> 6;
            const int c2 = (tid & 63) * 2;
            const int slot = fb_rows[min(base + r, nb - 1)];
            float2 v = *reinterpret_cast<const float2*>(x + (size_t)slot * DIM + c2);
            sx[r][c2] = v.x; sx[r][c2 + 1] = v.y;
        }
        __syncthreads();
        if (tid < 8) s_xn[tid] = np_sumsq_128(&sx[tid][0]);
        __syncthreads();

        float a0[8][4], a1[8][4];
        #pragma unroll
        for (int r = 0; r < 8; ++r)
            #pragma unroll
            for (int c = 0; c < 4; ++c) { a0[r][c] = 0.f; a1[r][c] = 0.f; }

        for (int q = 0; q < 32; ++q) {
            float4 ev0 = e0p[q];
            float4 ev1 = e1p[q];
            #pragma unroll
            for (int r = 0; r < 8; ++r) {
                float4 xv = *reinterpret_cast<const float4*>(&sx[r][q * 4]);
                a0[r][0] = fmaf(xv.x, ev0.x, a0[r][0]);
                a0[r][1] = fmaf(xv.y, ev0.y, a0[r][1]);
                a0[r][2] = fmaf(xv.z, ev0.z, a0[r][2]);
                a0[r][3] = fmaf(xv.w, ev0.w, a0[r][3]);
                a1[r][0] = fmaf(xv.x, ev1.x, a1[r][0]);
                a1[r][1] = fmaf(xv.y, ev1.y, a1[r][1]);
                a1[r][2] = fmaf(xv.z, ev1.z, a1[r][2]);
                a1[r][3] = fmaf(xv.w, ev1.w, a1[r][3]);
            }
        }

        float cv[8]; int ck[8];
        #pragma unroll
        for (int r = 0; r < 8; ++r) {
            float xn = s_xn[r];
            float d0 = __fadd_rn(__fadd_rn(a0[r][0], a0[r][1]),
                                 __fadd_rn(a0[r][2], a0[r][3]));
            float s0 = __fsub_rn(__fadd_rn(xn, en0), __fmul_rn(2.0f, d0));
            float d1 = __fadd_rn(__fadd_rn(a1[r][0], a1[r][1]),
                                 __fadd_rn(a1[r][2], a1[r][3]));
            float s1 = __fsub_rn(__fadd_rn(xn, en1), __fmul_rn(2.0f, d1));
            bool t1 = (s1 < s0);
            cv[r] = t1 ? s1 : s0;
            ck[r] = t1 ? tid + 512 : tid;
        }
        #pragma unroll
        for (int off = 1; off < 64; off <<= 1) {
            #pragma unroll
            for (int r = 0; r < 8; ++r) {
                float ov = __shfl_xor(cv[r], off, 64);
                int   ok = __shfl_xor(ck[r], off, 64);
                bool take = (ov < cv[r]) || (ov == cv[r] && ok < ck[r]);
                cv[r] = take ? ov : cv[r];
                ck[r] = take ? ok : ck[r];
            }
        }
        if (lane == 0) {
            #pragma unroll
            for (int r = 0; r < 8; ++r) { swv[wid][r] = cv[r]; swk[wid][r] = ck[r]; }
        }
        __syncthreads();
        if (tid < R) {
            float bv = swv[0][tid]; int bk = swk[0][tid];
            #pragma unroll
            for (int w = 1; w < 8; ++w) {
                float v = swv[w][tid]; int k = swk[w][tid];
                bool take = (v < bv) || (v == bv && k < bk);
                bv = take ? v : bv;
                bk = take ? k : bk;
            }
            const int row = fb_rows[base + tid];
            bestk[row] = bk;
            idx_out[row] = (float)bk;
        }
        __syncthreads();
    }
}

// ---- gather quantized rows + per-block loss partials (no atomics) ---------
__global__ __launch_bounds__(256) void vq_gather(
        const float* __restrict__ x, const float* __restrict__ emb,
        const int* __restrict__ bestk, float* __restrict__ quant,
        double* __restrict__ partials) {
    const int t = blockIdx.x * 256 + threadIdx.x;   // 1048576 threads, 8 elems
    const int r = t >> 4;
    const int c = (t & 15) * 8;
    const int bk = bestk[r];
    const float4* ep = reinterpret_cast<const float4*>(emb + (size_t)bk * DIM + c);
    const float4* xp = reinterpret_cast<const float4*>(x + (size_t)r * DIM + c);
    float4 e0 = ep[0], e1 = ep[1];
    float4 x0 = xp[0], x1 = xp[1];
    float* q = quant + (size_t)r * DIM + c;   // base misaligned by 1 float
    q[0] = e0.x; q[1] = e0.y; q[2] = e0.z; q[3] = e0.w;
    q[4] = e1.x; q[5] = e1.y; q[6] = e1.z; q[7] = e1.w;
    float d0 = e0.x - x0.x, d1 = e0.y - x0.y, d2 = e0.z - x0.z, d3 = e0.w - x0.w;
    float d4 = e1.x - x1.x, d5 = e1.y - x1.y, d6 = e1.z - x1.z, d7 = e1.w - x1.w;
    float acc = fmaf(d0, d0, fmaf(d1, d1, fmaf(d2, d2, d3 * d3)))
              + fmaf(d4, d4, fmaf(d5, d5, fmaf(d6, d6, d7 * d7)));
    #pragma unroll
    for (int off = 32; off > 0; off >>= 1) acc += __shfl_down(acc, off, 64);

    __shared__ float sacc[4];
    if ((threadIdx.x & 63) == 0) sacc[threadIdx.x >> 6] = acc;
    __syncthreads();
    if (threadIdx.x == 0)
        partials[blockIdx.x] =
            (double)sacc[0] + (double)sacc[1] + (double)sacc[2] + (double)sacc[3];
}

// ---- final loss: sum 4096 block partials in one block ---------------------
__global__ __launch_bounds__(256) void vq_loss(
        const double* __restrict__ partials, float* __restrict__ out) {
    double s = 0.0;
    #pragma unroll
    for (int i = 0; i < 16; ++i) s += partials[threadIdx.x + i * 256];
    #pragma unroll
    for (int off = 32; off > 0; off >>= 1) s += __shfl_down(s, off, 64);
    __shared__ double sd[4];
    if ((threadIdx.x & 63) == 0) sd[threadIdx.x >> 6] = s;
    __syncthreads();
    if (threadIdx.x == 0)
        out[0] = (float)((sd[0] + sd[1] + sd[2] + sd[3]) * (1.25 / 8388608.0));
}

extern "C" void kernel_launch(void* const* d_in, const int* in_sizes, int n_in,
                              void* d_out, int out_size, void* d_ws, size_t ws_size,
                              hipStream_t stream) {
    const float* x   = (const float*)d_in[0];   // [32,2048,128] f32
    const float* emb = (const float*)d_in[1];   // [1024,128] f32

    float* out      = (float*)d_out;
    float* loss_out = out;
    float* quant    = out + 1;                        // [8388608]
    float* idx_out  = out + 1 + (size_t)NROWS * DIM;  // [65536] as float

    char* ws = (char*)d_ws;
    int*    fb_cnt   = (int*)(ws + 8);
    float*  enorm    = (float*)(ws + 1024);             // 4 KB
    int*    fb_rows  = (int*)(ws + 16384);              // 256 KB
    int*    bestk    = (int*)(ws + 278528);             // 256 KB
    unsigned short* eh = (unsigned short*)(ws + 557056); // 256 KB
    unsigned short* em = (unsigned short*)(ws + 819200); // 256 KB
    double* partials = (double*)(ws + 1081344);          // 32 KB

    hipMemsetAsync(ws, 0, 16, stream);
    vq_prep<<<4, 256, 0, stream>>>(emb, enorm, eh, em);
    vq_mfma<<<512, 256, 0, stream>>>(x, eh, em, enorm,
                                     bestk, idx_out, fb_cnt, fb_rows);
    vq_fallback<<<1024, 512, 0, stream>>>(x, emb, enorm, fb_cnt, fb_rows,
                                          bestk, idx_out);
    vq_gather<<<4096, 256, 0, stream>>>(x, emb, bestk, quant, partials);
    vq_loss<<<1, 256, 0, stream>>>(partials, loss_out);
}